// Round 8
// baseline (1560.887 us; speedup 1.0000x reference)
//
#include <hip/hip_runtime.h>
#include <hip/hip_bf16.h>
#include <math.h>

#define NN 100000
#define NG 12500

using f32x4 = __attribute__((ext_vector_type(4))) float;
using bf16x8 = __attribute__((ext_vector_type(8))) __bf16;

__device__ __forceinline__ float warp_sum(float v) {
#pragma unroll
  for (int o = 32; o >= 1; o >>= 1) v += __shfl_xor(v, o);
  return v;
}

__device__ __forceinline__ float elu_f(float x) {
  return x > 0.f ? x : expm1f(x);
}

__device__ __forceinline__ ushort f2bf(float f) {
  unsigned u = __float_as_uint(f);
  u += 0x7FFFu + ((u >> 16) & 1u);
  return (ushort)(u >> 16);
}

// HW packed fp32->bf16 RNE: lo16 = bf16(a), hi16 = bf16(b)
__device__ __forceinline__ unsigned pkbf(float a, float b) {
  unsigned r;
  asm("v_cvt_pk_bf16_f32 %0, %1, %2" : "=v"(r) : "v"(a), "v"(b));
  return r;
}

__global__ __launch_bounds__(256) void cvt_bf16(const float* __restrict__ src,
                                                ushort* __restrict__ dst, int n4) {
  int i = blockIdx.x * 256 + threadIdx.x;
  if (i >= n4) return;
  float4 v = *reinterpret_cast<const float4*>(src + (size_t)i * 4);
  ushort4 o;
  o.x = f2bf(v.x); o.y = f2bf(v.y); o.z = f2bf(v.z); o.w = f2bf(v.w);
  *reinterpret_cast<ushort4*>(dst + (size_t)i * 4) = o;
}

// ---------------------------------------------------------------------------
// Per-wave GEMM: one 64-thread block = one wave = one 64x64 output tile.
// ZERO LDS, ZERO barriers. A-fragment layout (row=lane&15, k=lane>>4 * 8,
// contiguous) matches row-major A directly -> load A straight to registers
// (fp32: 2x float4 + cvt_pk; bf16: one 16B load). B bf16 direct from L2.
// Latency hiding via free-drifting waves (3/SIMD), not lockstep pipelining.
// Grid decode pins all NC col-blocks of a row-group to one XCD (id%8) so the
// NC-fold logical A re-read hits that XCD's L2.
// ---------------------------------------------------------------------------
template<bool A_BF16, bool RELU, int NC>
__global__ __launch_bounds__(64, 3) void gemm_pw(
    const void* __restrict__ Aptr, const ushort* __restrict__ Bptr,
    const float* __restrict__ bias, ushort* __restrict__ C,
    int M, int K, int Nc, int RB) {
  const int id = blockIdx.x;
  const int x = id & 7, g = id >> 3;
  const int cb = g % NC, rq = g / NC;
  const int rb = rq * 8 + x;
  if (rb >= RB) return;
  const int row0 = rb * 64, col0 = cb * 64;
  const int lane = threadIdx.x;
  const int lr = lane & 15, lg = lane >> 4;

  const ushort* Bp[4];
#pragma unroll
  for (int j = 0; j < 4; ++j)
    Bp[j] = Bptr + (size_t)(col0 + j * 16 + lr) * K + lg * 8;

  f32x4 acc[4][4] = {};

  if (A_BF16) {
    const ushort* A = (const ushort*)Aptr;
    const ushort* Ap[4];
#pragma unroll
    for (int i = 0; i < 4; ++i) {
      int r = row0 + i * 16 + lr;
      if (r > M - 1) r = M - 1;  // clamp; duplicate rows, guarded at store
      Ap[i] = A + (size_t)r * K + lg * 8;
    }
    for (int kt = 0; kt < K; kt += 64) {
#pragma unroll
      for (int ks = 0; ks < 2; ++ks) {
        bf16x8 a[4], b[4];
#pragma unroll
        for (int j = 0; j < 4; ++j)
          b[j] = *reinterpret_cast<const bf16x8*>(Bp[j] + kt + ks * 32);
#pragma unroll
        for (int i = 0; i < 4; ++i)
          a[i] = *reinterpret_cast<const bf16x8*>(Ap[i] + kt + ks * 32);
#pragma unroll
        for (int i = 0; i < 4; ++i)
#pragma unroll
          for (int j = 0; j < 4; ++j)
            acc[i][j] = __builtin_amdgcn_mfma_f32_16x16x32_bf16(a[i], b[j], acc[i][j], 0, 0, 0);
      }
    }
  } else {
    const float* A = (const float*)Aptr;
    const float* Ap[4];
#pragma unroll
    for (int i = 0; i < 4; ++i) {
      int r = row0 + i * 16 + lr;
      if (r > M - 1) r = M - 1;
      Ap[i] = A + (size_t)r * K + lg * 8;
    }
    for (int kt = 0; kt < K; kt += 64) {
#pragma unroll
      for (int ks = 0; ks < 2; ++ks) {
        bf16x8 a[4], b[4];
#pragma unroll
        for (int j = 0; j < 4; ++j)
          b[j] = *reinterpret_cast<const bf16x8*>(Bp[j] + kt + ks * 32);
#pragma unroll
        for (int i = 0; i < 4; ++i) {
          float4 p0 = *reinterpret_cast<const float4*>(Ap[i] + kt + ks * 32);
          float4 p1 = *reinterpret_cast<const float4*>(Ap[i] + kt + ks * 32 + 4);
          union { uint4 u; bf16x8 v; } cv;
          cv.u.x = pkbf(p0.x, p0.y); cv.u.y = pkbf(p0.z, p0.w);
          cv.u.z = pkbf(p1.x, p1.y); cv.u.w = pkbf(p1.z, p1.w);
          a[i] = cv.v;
        }
#pragma unroll
        for (int i = 0; i < 4; ++i)
#pragma unroll
          for (int j = 0; j < 4; ++j)
            acc[i][j] = __builtin_amdgcn_mfma_f32_16x16x32_bf16(a[i], b[j], acc[i][j], 0, 0, 0);
      }
    }
  }

  // epilogue: direct stores (lanes lr consecutive -> 32B runs per 16 lanes)
  float bs[4];
#pragma unroll
  for (int j = 0; j < 4; ++j) bs[j] = bias ? bias[col0 + j * 16 + lr] : 0.f;
#pragma unroll
  for (int i = 0; i < 4; ++i)
#pragma unroll
    for (int rr = 0; rr < 4; ++rr) {
      int row = row0 + i * 16 + lg * 4 + rr;
      if (row < M) {
#pragma unroll
        for (int j = 0; j < 4; ++j) {
          float v = acc[i][j][rr] + bs[j];
          if (RELU) v = fmaxf(v, 0.f);
          C[(size_t)row * Nc + col0 + j * 16 + lr] = f2bf(v);
        }
      }
    }
}

// x[:,0:128] = cat_table[cat_ids]; x[:,128:256] = LN(v2 bf16)
__global__ __launch_bounds__(256) void ln_concat(const ushort* __restrict__ v2,
    const float* __restrict__ g, const float* __restrict__ b,
    const int* __restrict__ cat_ids, const float* __restrict__ cat_table,
    float* __restrict__ x) {
  int w = (blockIdx.x * blockDim.x + threadIdx.x) >> 6;
  int lane = threadIdx.x & 63;
  if (w >= NN) return;
  unsigned raw = *reinterpret_cast<const unsigned*>(v2 + (size_t)w * 128 + lane * 2);
  float ax = __uint_as_float(raw << 16);
  float ay = __uint_as_float(raw & 0xFFFF0000u);
  float s = ax + ay, s2 = ax * ax + ay * ay;
  s = warp_sum(s); s2 = warp_sum(s2);
  float mu = s * (1.f / 128.f);
  float var = s2 * (1.f / 128.f) - mu * mu;
  float rs = rsqrtf(var + 1e-5f);
  float2 gg = *reinterpret_cast<const float2*>(g + lane * 2);
  float2 bb = *reinterpret_cast<const float2*>(b + lane * 2);
  float2 o;
  o.x = (ax - mu) * rs * gg.x + bb.x;
  o.y = (ay - mu) * rs * gg.y + bb.y;
  *reinterpret_cast<float2*>(x + (size_t)w * 256 + 128 + lane * 2) = o;
  int cid = cat_ids[w];
  *reinterpret_cast<float2*>(x + (size_t)w * 256 + lane * 2) =
      *reinterpret_cast<const float2*>(cat_table + (size_t)cid * 128 + lane * 2);
}

// fused GAT: scores + 8x8 softmax + aggregate + bias + elu + residual + LN.
template<int H>
__global__ __launch_bounds__(256) void gat_fused(const ushort* __restrict__ h,
    const float* __restrict__ asv, const float* __restrict__ adv,
    const float* __restrict__ bias, const float* __restrict__ lng,
    const float* __restrict__ lnb, float* __restrict__ x) {
  constexpr int C = 256 / H;
  constexpr int GROUP = C / 4;
  __shared__ __align__(16) float hs[4][8][256];
  __shared__ float attS[4][8][H], attD[4][8][H];
  const int wid = threadIdx.x >> 6, lane = threadIdx.x & 63;
  const int g = blockIdx.x * 4 + wid;
  const int base = g * 8;
  const int hd = lane / GROUP;
  float4 as4 = *reinterpret_cast<const float4*>(asv + lane * 4);
  float4 ad4 = *reinterpret_cast<const float4*>(adv + lane * 4);
#pragma unroll
  for (int i = 0; i < 8; ++i) {
    uint2 raw = *reinterpret_cast<const uint2*>(h + (size_t)(base + i) * 256 + lane * 4);
    float f0 = __uint_as_float(raw.x << 16);
    float f1 = __uint_as_float(raw.x & 0xFFFF0000u);
    float f2 = __uint_as_float(raw.y << 16);
    float f3 = __uint_as_float(raw.y & 0xFFFF0000u);
    *reinterpret_cast<float4*>(&hs[wid][i][lane * 4]) = make_float4(f0, f1, f2, f3);
    float ps = f0 * as4.x + f1 * as4.y + f2 * as4.z + f3 * as4.w;
    float pd = f0 * ad4.x + f1 * ad4.y + f2 * ad4.z + f3 * ad4.w;
#pragma unroll
    for (int o = GROUP / 2; o >= 1; o >>= 1) {
      ps += __shfl_xor(ps, o);
      pd += __shfl_xor(pd, o);
    }
    if ((lane & (GROUP - 1)) == 0) {
      attS[wid][i][hd] = ps;
      attD[wid][i][hd] = pd;
    }
  }
  __syncthreads();
  const float4 gv = *reinterpret_cast<const float4*>(lng + lane * 4);
  const float4 bv = *reinterpret_cast<const float4*>(lnb + lane * 4);
  const float4 biasv = *reinterpret_cast<const float4*>(bias + lane * 4);
  for (int i = 0; i < 8; ++i) {
    float ad = attD[wid][i][hd];
    float e[8];
    float mx = -1e30f;
#pragma unroll
    for (int j = 0; j < 8; ++j) {
      float v = attS[wid][j][hd] + ad;
      v = v > 0.f ? v : 0.2f * v;
      e[j] = v;
      mx = fmaxf(mx, v);
    }
    float sum = 0.f;
#pragma unroll
    for (int j = 0; j < 8; ++j) { e[j] = expf(e[j] - mx); sum += e[j]; }
    float inv = 1.f / (sum + 1e-16f);
    float a0 = 0, a1 = 0, a2 = 0, a3 = 0;
#pragma unroll
    for (int j = 0; j < 8; ++j) {
      float wj = e[j] * inv;
      float4 hv = *reinterpret_cast<const float4*>(&hs[wid][j][lane * 4]);
      a0 += wj * hv.x; a1 += wj * hv.y; a2 += wj * hv.z; a3 += wj * hv.w;
    }
    float4 xr = *reinterpret_cast<const float4*>(x + (size_t)(base + i) * 256 + lane * 4);
    float v0 = elu_f(a0 + biasv.x) + xr.x;
    float v1 = elu_f(a1 + biasv.y) + xr.y;
    float v2 = elu_f(a2 + biasv.z) + xr.z;
    float v3 = elu_f(a3 + biasv.w) + xr.w;
    float s = v0 + v1 + v2 + v3;
    float s2 = v0 * v0 + v1 * v1 + v2 * v2 + v3 * v3;
    s = warp_sum(s); s2 = warp_sum(s2);
    float mu = s * (1.f / 256.f);
    float var = s2 * (1.f / 256.f) - mu * mu;
    float rs = rsqrtf(var + 1e-5f);
    float4 o;
    o.x = (v0 - mu) * rs * gv.x + bv.x;
    o.y = (v1 - mu) * rs * gv.y + bv.y;
    o.z = (v2 - mu) * rs * gv.z + bv.z;
    o.w = (v3 - mu) * rs * gv.w + bv.w;
    *reinterpret_cast<float4*>(x + (size_t)(base + i) * 256 + lane * 4) = o;
  }
}

__global__ __launch_bounds__(256) void pool_readout(const float* __restrict__ x,
    const float* __restrict__ rw, const float* __restrict__ rb,
    float* __restrict__ out) {
  int g = (blockIdx.x * blockDim.x + threadIdx.x) >> 6;
  int lane = threadIdx.x & 63;
  if (g >= NG) return;
  float a0 = 0, a1 = 0, a2 = 0, a3 = 0;
#pragma unroll
  for (int j = 0; j < 8; ++j) {
    float4 v = *reinterpret_cast<const float4*>(x + (size_t)(g * 8 + j) * 256 + lane * 4);
    a0 += v.x; a1 += v.y; a2 += v.z; a3 += v.w;
  }
  float4 w = *reinterpret_cast<const float4*>(rw + lane * 4);
  float p = (a0 * w.x + a1 * w.y + a2 * w.z + a3 * w.w) * 0.125f;
  p = warp_sum(p);
  if (lane == 0) out[g] = 1.f / (1.f + expf(-(p + rb[0])));
}

extern "C" void kernel_launch(void* const* d_in, const int* in_sizes, int n_in,
                              void* d_out, int out_size, void* d_ws, size_t ws_size,
                              hipStream_t stream) {
  const int* cat_ids = (const int*)d_in[0];
  const float* vf = (const float*)d_in[1];
  const float* cat_table = (const float*)d_in[4];
  const float* vp_w1 = (const float*)d_in[5];
  const float* vp_b1 = (const float*)d_in[6];
  const float* vp_w2 = (const float*)d_in[7];
  const float* vp_b2 = (const float*)d_in[8];
  const float* vp_lng = (const float*)d_in[9];
  const float* vp_lnb = (const float*)d_in[10];
  const float* c0_w = (const float*)d_in[11];
  const float* c0_as = (const float*)d_in[12];
  const float* c0_ad = (const float*)d_in[13];
  const float* c0_b = (const float*)d_in[14];
  const float* ln0_g = (const float*)d_in[15];
  const float* ln0_b = (const float*)d_in[16];
  const float* c1_w = (const float*)d_in[17];
  const float* c1_as = (const float*)d_in[18];
  const float* c1_ad = (const float*)d_in[19];
  const float* c1_b = (const float*)d_in[20];
  const float* ln1_g = (const float*)d_in[21];
  const float* ln1_b = (const float*)d_in[22];
  const float* ro_w = (const float*)d_in[23];
  const float* ro_b = (const float*)d_in[24];
  float* out = (float*)d_out;

  char* ws = (char*)d_ws;
  ushort* w1b = (ushort*)ws;   ws += (size_t)512 * 2048 * 2;
  ushort* w2b = (ushort*)ws;   ws += (size_t)128 * 512 * 2;
  ushort* c0wb = (ushort*)ws;  ws += (size_t)256 * 256 * 2;
  ushort* c1wb = (ushort*)ws;  ws += (size_t)256 * 256 * 2;
  ushort* v1b = (ushort*)ws;   ws += (size_t)NN * 512 * 2;
  ushort* v2b = (ushort*)ws;   ws += (size_t)NN * 128 * 2;
  ushort* hbb = (ushort*)ws;   ws += (size_t)NN * 256 * 2;
  float* xb = (float*)ws;

  dim3 b256(256), b64(64);
  const int RB = (NN + 63) / 64;          // 1563
  const int RBpad = ((RB + 7) / 8) * 8;   // 1568

  cvt_bf16<<<1024, b256, 0, stream>>>(vp_w1, w1b, 512 * 2048 / 4);
  cvt_bf16<<<64, b256, 0, stream>>>(vp_w2, w2b, 128 * 512 / 4);
  cvt_bf16<<<64, b256, 0, stream>>>(c0_w, c0wb, 256 * 256 / 4);
  cvt_bf16<<<64, b256, 0, stream>>>(c1_w, c1wb, 256 * 256 / 4);

  // v1 = relu(vf @ w1^T + b1): fp32 A, 512 cols -> NC=8
  gemm_pw<false, true, 8><<<RBpad * 8, b64, 0, stream>>>(vf, w1b, vp_b1, v1b,
                                                         NN, 2048, 512, RB);
  // v2 = v1 @ w2^T + b2: bf16 A, 128 cols -> NC=2
  gemm_pw<true, false, 2><<<RBpad * 2, b64, 0, stream>>>(v1b, w2b, vp_b2, v2b,
                                                         NN, 512, 128, RB);
  ln_concat<<<(NN * 64 + 255) / 256, b256, 0, stream>>>(v2b, vp_lng, vp_lnb,
                                                        cat_ids, cat_table, xb);

  gemm_pw<false, false, 4><<<RBpad * 4, b64, 0, stream>>>(xb, c0wb, nullptr, hbb,
                                                          NN, 256, 256, RB);
  gat_fused<4><<<NG / 4, b256, 0, stream>>>(hbb, c0_as, c0_ad, c0_b, ln0_g, ln0_b, xb);

  gemm_pw<false, false, 4><<<RBpad * 4, b64, 0, stream>>>(xb, c1wb, nullptr, hbb,
                                                          NN, 256, 256, RB);
  gat_fused<1><<<NG / 4, b256, 0, stream>>>(hbb, c1_as, c1_ad, c1_b, ln1_g, ln1_b, xb);

  pool_readout<<<NG / 4, b256, 0, stream>>>(xb, ro_w, ro_b, out);
}

// Round 9
// 740.275 us; speedup vs baseline: 2.1085x; 2.1085x over previous
//
#include <hip/hip_runtime.h>
#include <hip/hip_bf16.h>
#include <math.h>

#define NN 100000
#define NG 12500

using f32x4 = __attribute__((ext_vector_type(4))) float;
using bf16x8 = __attribute__((ext_vector_type(8))) __bf16;

__device__ __forceinline__ float warp_sum(float v) {
#pragma unroll
  for (int o = 32; o >= 1; o >>= 1) v += __shfl_xor(v, o);
  return v;
}

__device__ __forceinline__ float elu_f(float x) {
  return x > 0.f ? x : expm1f(x);
}

__device__ __forceinline__ ushort f2bf(float f) {
  unsigned u = __float_as_uint(f);
  u += 0x7FFFu + ((u >> 16) & 1u);
  return (ushort)(u >> 16);
}

// HW packed fp32->bf16 RNE: lo16 = bf16(a), hi16 = bf16(b)
__device__ __forceinline__ unsigned pkbf(float a, float b) {
  unsigned r;
  asm("v_cvt_pk_bf16_f32 %0, %1, %2" : "=v"(r) : "v"(a), "v"(b));
  return r;
}

// swizzled byte offset into a [row][64 bf16] LDS tile (row stride 128 B)
__device__ __forceinline__ int swz(int row, int kbyte) {
  return row * 128 + (kbyte ^ ((row & 7) << 4));
}

__global__ __launch_bounds__(256) void cvt_bf16(const float* __restrict__ src,
                                                ushort* __restrict__ dst, int n4) {
  int i = blockIdx.x * 256 + threadIdx.x;
  if (i >= n4) return;
  float4 v = *reinterpret_cast<const float4*>(src + (size_t)i * 4);
  ushort4 o;
  o.x = f2bf(v.x); o.y = f2bf(v.y); o.z = f2bf(v.z); o.w = f2bf(v.w);
  *reinterpret_cast<ushort4*>(dst + (size_t)i * 4) = o;
}

// grid-stride streaming fp32 -> bf16 (8 elems/thread/iter), HBM-saturating
__global__ __launch_bounds__(256) void cvt_stream(const float* __restrict__ src,
                                                  ushort* __restrict__ dst, long n8) {
  long stride = (long)gridDim.x * 256;
  for (long i = (long)blockIdx.x * 256 + threadIdx.x; i < n8; i += stride) {
    float4 a = *reinterpret_cast<const float4*>(src + i * 8);
    float4 b = *reinterpret_cast<const float4*>(src + i * 8 + 4);
    uint4 o;
    o.x = pkbf(a.x, a.y); o.y = pkbf(a.z, a.w);
    o.z = pkbf(b.x, b.y); o.w = pkbf(b.z, b.w);
    *reinterpret_cast<uint4*>(dst + i * 8) = o;
  }
}

#define MM(i, j, a, b) \
  acc[i][j] = __builtin_amdgcn_mfma_f32_16x16x32_bf16(a, b, acc[i][j], 0, 0, 0)

// ---------------------------------------------------------------------------
// m97-style bf16 GEMM: 128x128 tile, BK=64, 4 waves (2x2 of 64x64).
// A and B both staged via global_load_lds width-16 (pre-swizzled global src,
// linear LDS dest), single-buffered 32KB, 2 barriers/K-step, 3 blocks/CU.
// Grid decode pins all NC col-blocks of a row-group to one XCD (id&7) so the
// NC-fold A re-read hits that XCD's L2.   C = act(A[M,K] @ B[Nc,K]^T + bias)
// ---------------------------------------------------------------------------
template<bool RELU, int NC>
__global__ __launch_bounds__(256, 3) void gemm_glds(
    const ushort* __restrict__ A, const ushort* __restrict__ B,
    const float* __restrict__ bias, ushort* __restrict__ C,
    int M, int K, int Nc, int RB) {
  __shared__ char smem[128 * 136 * 2];  // 34816; staging uses first 32KB
  int rb, cb;
  if (NC == 1) {
    rb = blockIdx.x; cb = 0;
  } else {
    int id = blockIdx.x;
    int x = id & 7, g = id >> 3;
    cb = g % NC;
    rb = (g / NC) * 8 + x;
  }
  if (rb >= RB) return;
  const int row0 = rb * 128, col0 = cb * 128;
  const int tid = threadIdx.x, wid = tid >> 6, lane = tid & 63;
  const int lr = lane & 15, lg = lane >> 4;
  const int wm = (wid >> 1) * 64, wn = (wid & 1) * 64;
  char* AsB = smem;
  char* BsB = smem + 16384;
  const int mrows = (M - row0 < 128) ? (M - row0) : 128;

#define STAGEOP(buf, base, rowoff, kt, nval)                                    \
  do {                                                                          \
    _Pragma("unroll")                                                           \
    for (int u = 0; u < 4; ++u) {                                               \
      int unit = u * 256 + tid;                                                 \
      int drow = unit >> 3, dkg = unit & 7;                                     \
      const ushort* src = (base) + (size_t)((rowoff) + drow) * K + (kt) +       \
                          (((dkg * 16) ^ ((drow & 7) << 4)) >> 1);              \
      if (drow < (nval))                                                        \
        __builtin_amdgcn_global_load_lds(src, (buf) + u * 4096 + wid * 1024,    \
                                         16, 0, 0);                             \
    }                                                                           \
  } while (0)

  f32x4 acc[4][4] = {};
  for (int kt = 0; kt < K; kt += 64) {
    STAGEOP(AsB, A, row0, kt, mrows);
    STAGEOP(BsB, B, col0, kt, 128);
    __syncthreads();  // compiler drains vmcnt before s_barrier
#pragma unroll
    for (int ks = 0; ks < 2; ++ks) {
      bf16x8 a0 = *reinterpret_cast<const bf16x8*>(AsB + swz(wm + 0 + lr, ks * 64 + lg * 16));
      bf16x8 a1 = *reinterpret_cast<const bf16x8*>(AsB + swz(wm + 16 + lr, ks * 64 + lg * 16));
      bf16x8 a2 = *reinterpret_cast<const bf16x8*>(AsB + swz(wm + 32 + lr, ks * 64 + lg * 16));
      bf16x8 a3 = *reinterpret_cast<const bf16x8*>(AsB + swz(wm + 48 + lr, ks * 64 + lg * 16));
      bf16x8 b0 = *reinterpret_cast<const bf16x8*>(BsB + swz(wn + 0 + lr, ks * 64 + lg * 16));
      bf16x8 b1 = *reinterpret_cast<const bf16x8*>(BsB + swz(wn + 16 + lr, ks * 64 + lg * 16));
      bf16x8 b2 = *reinterpret_cast<const bf16x8*>(BsB + swz(wn + 32 + lr, ks * 64 + lg * 16));
      bf16x8 b3 = *reinterpret_cast<const bf16x8*>(BsB + swz(wn + 48 + lr, ks * 64 + lg * 16));
      MM(0, 0, a0, b0); MM(0, 1, a0, b1); MM(0, 2, a0, b2); MM(0, 3, a0, b3);
      MM(1, 0, a1, b0); MM(1, 1, a1, b1); MM(1, 2, a1, b2); MM(1, 3, a1, b3);
      MM(2, 0, a2, b0); MM(2, 1, a2, b1); MM(2, 2, a2, b2); MM(2, 3, a2, b3);
      MM(3, 0, a3, b0); MM(3, 1, a3, b1); MM(3, 2, a3, b2); MM(3, 3, a3, b3);
    }
    __syncthreads();
  }
#undef STAGEOP
  // epilogue: acc -> LDS bf16 (stride 136) -> coalesced 16B stores
  ushort* Cs = reinterpret_cast<ushort*>(smem);
#pragma unroll
  for (int j = 0; j < 4; ++j) {
    float bv = bias ? bias[col0 + wn + j * 16 + lr] : 0.f;
#pragma unroll
    for (int i = 0; i < 4; ++i)
#pragma unroll
      for (int r = 0; r < 4; ++r) {
        float v = acc[i][j][r] + bv;
        if (RELU) v = fmaxf(v, 0.f);
        Cs[(wm + i * 16 + lg * 4 + r) * 136 + wn + j * 16 + lr] = f2bf(v);
      }
  }
  __syncthreads();
#pragma unroll
  for (int u = 0; u < 8; ++u) {
    int unit = tid + u * 256;
    int r = unit >> 4, cg = unit & 15;
    int grow = row0 + r;
    if (grow < M)
      *reinterpret_cast<uint4*>(C + (size_t)grow * Nc + col0 + cg * 8) =
          *reinterpret_cast<const uint4*>(Cs + r * 136 + cg * 8);
  }
}

// x fp32 + xb16 bf16 dual-write; x[:,0:128]=cat_emb, x[:,128:256]=LN(v2)
__global__ __launch_bounds__(256) void ln_concat(const ushort* __restrict__ v2,
    const float* __restrict__ g, const float* __restrict__ b,
    const int* __restrict__ cat_ids, const float* __restrict__ cat_table,
    float* __restrict__ x, ushort* __restrict__ xb16) {
  int w = (blockIdx.x * blockDim.x + threadIdx.x) >> 6;
  int lane = threadIdx.x & 63;
  if (w >= NN) return;
  unsigned raw = *reinterpret_cast<const unsigned*>(v2 + (size_t)w * 128 + lane * 2);
  float ax = __uint_as_float(raw << 16);
  float ay = __uint_as_float(raw & 0xFFFF0000u);
  float s = ax + ay, s2 = ax * ax + ay * ay;
  s = warp_sum(s); s2 = warp_sum(s2);
  float mu = s * (1.f / 128.f);
  float var = s2 * (1.f / 128.f) - mu * mu;
  float rs = rsqrtf(var + 1e-5f);
  float2 gg = *reinterpret_cast<const float2*>(g + lane * 2);
  float2 bb = *reinterpret_cast<const float2*>(b + lane * 2);
  float2 o;
  o.x = (ax - mu) * rs * gg.x + bb.x;
  o.y = (ay - mu) * rs * gg.y + bb.y;
  *reinterpret_cast<float2*>(x + (size_t)w * 256 + 128 + lane * 2) = o;
  *reinterpret_cast<unsigned*>(xb16 + (size_t)w * 256 + 128 + lane * 2) = pkbf(o.x, o.y);
  int cid = cat_ids[w];
  float2 ce = *reinterpret_cast<const float2*>(cat_table + (size_t)cid * 128 + lane * 2);
  *reinterpret_cast<float2*>(x + (size_t)w * 256 + lane * 2) = ce;
  *reinterpret_cast<unsigned*>(xb16 + (size_t)w * 256 + lane * 2) = pkbf(ce.x, ce.y);
}

// fused GAT: scores + 8x8 softmax + aggregate + bias + elu + residual + LN.
// reads h bf16, residual x fp32; writes x fp32 + xb16 bf16.
template<int H>
__global__ __launch_bounds__(256) void gat_fused(const ushort* __restrict__ h,
    const float* __restrict__ asv, const float* __restrict__ adv,
    const float* __restrict__ bias, const float* __restrict__ lng,
    const float* __restrict__ lnb, float* __restrict__ x,
    ushort* __restrict__ xb16) {
  constexpr int C = 256 / H;
  constexpr int GROUP = C / 4;
  __shared__ __align__(16) float hs[4][8][256];
  __shared__ float attS[4][8][H], attD[4][8][H];
  const int wid = threadIdx.x >> 6, lane = threadIdx.x & 63;
  const int g = blockIdx.x * 4 + wid;
  const int base = g * 8;
  const int hd = lane / GROUP;
  float4 as4 = *reinterpret_cast<const float4*>(asv + lane * 4);
  float4 ad4 = *reinterpret_cast<const float4*>(adv + lane * 4);
#pragma unroll
  for (int i = 0; i < 8; ++i) {
    uint2 raw = *reinterpret_cast<const uint2*>(h + (size_t)(base + i) * 256 + lane * 4);
    float f0 = __uint_as_float(raw.x << 16);
    float f1 = __uint_as_float(raw.x & 0xFFFF0000u);
    float f2 = __uint_as_float(raw.y << 16);
    float f3 = __uint_as_float(raw.y & 0xFFFF0000u);
    *reinterpret_cast<float4*>(&hs[wid][i][lane * 4]) = make_float4(f0, f1, f2, f3);
    float ps = f0 * as4.x + f1 * as4.y + f2 * as4.z + f3 * as4.w;
    float pd = f0 * ad4.x + f1 * ad4.y + f2 * ad4.z + f3 * ad4.w;
#pragma unroll
    for (int o = GROUP / 2; o >= 1; o >>= 1) {
      ps += __shfl_xor(ps, o);
      pd += __shfl_xor(pd, o);
    }
    if ((lane & (GROUP - 1)) == 0) {
      attS[wid][i][hd] = ps;
      attD[wid][i][hd] = pd;
    }
  }
  __syncthreads();
  const float4 gv = *reinterpret_cast<const float4*>(lng + lane * 4);
  const float4 bv = *reinterpret_cast<const float4*>(lnb + lane * 4);
  const float4 biasv = *reinterpret_cast<const float4*>(bias + lane * 4);
  for (int i = 0; i < 8; ++i) {
    float ad = attD[wid][i][hd];
    float e[8];
    float mx = -1e30f;
#pragma unroll
    for (int j = 0; j < 8; ++j) {
      float v = attS[wid][j][hd] + ad;
      v = v > 0.f ? v : 0.2f * v;
      e[j] = v;
      mx = fmaxf(mx, v);
    }
    float sum = 0.f;
#pragma unroll
    for (int j = 0; j < 8; ++j) { e[j] = expf(e[j] - mx); sum += e[j]; }
    float inv = 1.f / (sum + 1e-16f);
    float a0 = 0, a1 = 0, a2 = 0, a3 = 0;
#pragma unroll
    for (int j = 0; j < 8; ++j) {
      float wj = e[j] * inv;
      float4 hv = *reinterpret_cast<const float4*>(&hs[wid][j][lane * 4]);
      a0 += wj * hv.x; a1 += wj * hv.y; a2 += wj * hv.z; a3 += wj * hv.w;
    }
    float4 xr = *reinterpret_cast<const float4*>(x + (size_t)(base + i) * 256 + lane * 4);
    float v0 = elu_f(a0 + biasv.x) + xr.x;
    float v1 = elu_f(a1 + biasv.y) + xr.y;
    float v2 = elu_f(a2 + biasv.z) + xr.z;
    float v3 = elu_f(a3 + biasv.w) + xr.w;
    float s = v0 + v1 + v2 + v3;
    float s2 = v0 * v0 + v1 * v1 + v2 * v2 + v3 * v3;
    s = warp_sum(s); s2 = warp_sum(s2);
    float mu = s * (1.f / 256.f);
    float var = s2 * (1.f / 256.f) - mu * mu;
    float rs = rsqrtf(var + 1e-5f);
    float4 o;
    o.x = (v0 - mu) * rs * gv.x + bv.x;
    o.y = (v1 - mu) * rs * gv.y + bv.y;
    o.z = (v2 - mu) * rs * gv.z + bv.z;
    o.w = (v3 - mu) * rs * gv.w + bv.w;
    *reinterpret_cast<float4*>(x + (size_t)(base + i) * 256 + lane * 4) = o;
    uint2 ob;
    ob.x = pkbf(o.x, o.y);
    ob.y = pkbf(o.z, o.w);
    *reinterpret_cast<uint2*>(xb16 + (size_t)(base + i) * 256 + lane * 4) = ob;
  }
}

__global__ __launch_bounds__(256) void pool_readout(const float* __restrict__ x,
    const float* __restrict__ rw, const float* __restrict__ rb,
    float* __restrict__ out) {
  int g = (blockIdx.x * blockDim.x + threadIdx.x) >> 6;
  int lane = threadIdx.x & 63;
  if (g >= NG) return;
  float a0 = 0, a1 = 0, a2 = 0, a3 = 0;
#pragma unroll
  for (int j = 0; j < 8; ++j) {
    float4 v = *reinterpret_cast<const float4*>(x + (size_t)(g * 8 + j) * 256 + lane * 4);
    a0 += v.x; a1 += v.y; a2 += v.z; a3 += v.w;
  }
  float4 w = *reinterpret_cast<const float4*>(rw + lane * 4);
  float p = (a0 * w.x + a1 * w.y + a2 * w.z + a3 * w.w) * 0.125f;
  p = warp_sum(p);
  if (lane == 0) out[g] = 1.f / (1.f + expf(-(p + rb[0])));
}

extern "C" void kernel_launch(void* const* d_in, const int* in_sizes, int n_in,
                              void* d_out, int out_size, void* d_ws, size_t ws_size,
                              hipStream_t stream) {
  const int* cat_ids = (const int*)d_in[0];
  const float* vf = (const float*)d_in[1];
  const float* cat_table = (const float*)d_in[4];
  const float* vp_w1 = (const float*)d_in[5];
  const float* vp_b1 = (const float*)d_in[6];
  const float* vp_w2 = (const float*)d_in[7];
  const float* vp_b2 = (const float*)d_in[8];
  const float* vp_lng = (const float*)d_in[9];
  const float* vp_lnb = (const float*)d_in[10];
  const float* c0_w = (const float*)d_in[11];
  const float* c0_as = (const float*)d_in[12];
  const float* c0_ad = (const float*)d_in[13];
  const float* c0_b = (const float*)d_in[14];
  const float* ln0_g = (const float*)d_in[15];
  const float* ln0_b = (const float*)d_in[16];
  const float* c1_w = (const float*)d_in[17];
  const float* c1_as = (const float*)d_in[18];
  const float* c1_ad = (const float*)d_in[19];
  const float* c1_b = (const float*)d_in[20];
  const float* ln1_g = (const float*)d_in[21];
  const float* ln1_b = (const float*)d_in[22];
  const float* ro_w = (const float*)d_in[23];
  const float* ro_b = (const float*)d_in[24];
  float* out = (float*)d_out;

  char* ws = (char*)d_ws;
  ushort* w1b = (ushort*)ws;   ws += (size_t)512 * 2048 * 2;
  ushort* w2b = (ushort*)ws;   ws += (size_t)128 * 512 * 2;
  ushort* c0wb = (ushort*)ws;  ws += (size_t)256 * 256 * 2;
  ushort* c1wb = (ushort*)ws;  ws += (size_t)256 * 256 * 2;
  ushort* v1b = (ushort*)ws;   ws += (size_t)NN * 512 * 2;
  ushort* v2b = (ushort*)ws;   ws += (size_t)NN * 128 * 2;
  // vfb region (400MB) is reused after GEMM2 for xb/xb16/hbb
  char* big = ws;
  ushort* vfb = (ushort*)big;                       // [NN,2048] bf16
  float* xb = (float*)big;                          // [NN,256] fp32 (aliases vfb)
  ushort* xbb = (ushort*)(big + (size_t)NN * 256 * 4);   // [NN,256] bf16
  ushort* hbb = (ushort*)(big + (size_t)NN * 256 * 6);   // [NN,256] bf16

  dim3 b256(256);
  const int RB = (NN + 127) / 128;        // 782
  const int RBpad = ((RB + 7) / 8) * 8;   // 784

  // streaming fp32->bf16 of visual_feats (HBM-bound, ~190us)
  cvt_stream<<<2048, b256, 0, stream>>>(vf, vfb, (long)NN * 2048 / 8);
  cvt_bf16<<<1024, b256, 0, stream>>>(vp_w1, w1b, 512 * 2048 / 4);
  cvt_bf16<<<64, b256, 0, stream>>>(vp_w2, w2b, 128 * 512 / 4);
  cvt_bf16<<<64, b256, 0, stream>>>(c0_w, c0wb, 256 * 256 / 4);
  cvt_bf16<<<64, b256, 0, stream>>>(c1_w, c1wb, 256 * 256 / 4);

  // v1 = relu(vfb @ w1^T + b1): NC=4 col-blocks XCD-paired
  gemm_glds<true, 4><<<RBpad * 4, b256, 0, stream>>>(vfb, w1b, vp_b1, v1b,
                                                     NN, 2048, 512, RB);
  // v2 = v1 @ w2^T + b2
  gemm_glds<false, 1><<<RB, b256, 0, stream>>>(v1b, w2b, vp_b2, v2b,
                                               NN, 512, 128, RB);
  // vfb dead from here; xb/xbb/hbb alias its region
  ln_concat<<<(NN * 64 + 255) / 256, b256, 0, stream>>>(v2b, vp_lng, vp_lnb,
                                                        cat_ids, cat_table, xb, xbb);

  gemm_glds<false, 2><<<RBpad * 2, b256, 0, stream>>>(xbb, c0wb, nullptr, hbb,
                                                      NN, 256, 256, RB);
  gat_fused<4><<<NG / 4, b256, 0, stream>>>(hbb, c0_as, c0_ad, c0_b, ln0_g, ln0_b, xb, xbb);

  gemm_glds<false, 2><<<RBpad * 2, b256, 0, stream>>>(xbb, c1wb, nullptr, hbb,
                                                      NN, 256, 256, RB);
  gat_fused<1><<<NG / 4, b256, 0, stream>>>(hbb, c1_as, c1_ad, c1_b, ln1_g, ln1_b, xb, xbb);

  pool_readout<<<NG / 4, b256, 0, stream>>>(xb, ro_w, ro_b, out);
}

// Round 10
// 674.520 us; speedup vs baseline: 2.3141x; 1.0975x over previous
//
#include <hip/hip_runtime.h>
#include <hip/hip_bf16.h>
#include <math.h>

#define NN 100000
#define NG 12500

using f32x4 = __attribute__((ext_vector_type(4))) float;
using bf16x8 = __attribute__((ext_vector_type(8))) __bf16;

__device__ __forceinline__ float warp_sum(float v) {
#pragma unroll
  for (int o = 32; o >= 1; o >>= 1) v += __shfl_xor(v, o);
  return v;
}

__device__ __forceinline__ float elu_f(float x) {
  return x > 0.f ? x : expm1f(x);
}

__device__ __forceinline__ ushort f2bf(float f) {
  unsigned u = __float_as_uint(f);
  u += 0x7FFFu + ((u >> 16) & 1u);
  return (ushort)(u >> 16);
}

// HW packed fp32->bf16 RNE: lo16 = bf16(a), hi16 = bf16(b)
__device__ __forceinline__ unsigned pkbf(float a, float b) {
  unsigned r;
  asm("v_cvt_pk_bf16_f32 %0, %1, %2" : "=v"(r) : "v"(a), "v"(b));
  return r;
}

// swizzled byte offset into a [row][64 bf16] LDS tile (row stride 128 B)
__device__ __forceinline__ int swz(int row, int kbyte) {
  return row * 128 + (kbyte ^ ((row & 7) << 4));
}

__global__ __launch_bounds__(256) void cvt_bf16(const float* __restrict__ src,
                                                ushort* __restrict__ dst, int n4) {
  int i = blockIdx.x * 256 + threadIdx.x;
  if (i >= n4) return;
  float4 v = *reinterpret_cast<const float4*>(src + (size_t)i * 4);
  ushort4 o;
  o.x = f2bf(v.x); o.y = f2bf(v.y); o.z = f2bf(v.z); o.w = f2bf(v.w);
  *reinterpret_cast<ushort4*>(dst + (size_t)i * 4) = o;
}

#define MM(i, j, a, b) \
  acc[i][j] = __builtin_amdgcn_mfma_f32_16x16x32_bf16(a, b, acc[i][j], 0, 0, 0)

// B staging via global_load_lds (pre-swizzled source, linear LDS dest)
#define STAGEB(buf, base, rowoff, kt, K)                                        \
  do {                                                                          \
    _Pragma("unroll")                                                           \
    for (int u = 0; u < 4; ++u) {                                               \
      int unit = u * 256 + tid;                                                 \
      int drow = unit >> 3, dkg = unit & 7;                                     \
      const ushort* src = (base) + (size_t)((rowoff) + drow) * (K) + (kt) +     \
                          (((dkg * 16) ^ ((drow & 7) << 4)) >> 1);              \
      __builtin_amdgcn_global_load_lds(src, (buf) + u * 4096 + wid * 1024,      \
                                       16, 0, 0);                               \
    }                                                                           \
  } while (0)

// MFMA inner block over one staged K-step (both A,B bf16 in LDS)
#define MFMABLOCK(AsB, BsB)                                                     \
  do {                                                                          \
    _Pragma("unroll")                                                           \
    for (int ks = 0; ks < 2; ++ks) {                                            \
      bf16x8 a0 = *reinterpret_cast<const bf16x8*>((AsB) + swz(wm + 0 + lr, ks * 64 + lg * 16));  \
      bf16x8 a1 = *reinterpret_cast<const bf16x8*>((AsB) + swz(wm + 16 + lr, ks * 64 + lg * 16)); \
      bf16x8 a2 = *reinterpret_cast<const bf16x8*>((AsB) + swz(wm + 32 + lr, ks * 64 + lg * 16)); \
      bf16x8 a3 = *reinterpret_cast<const bf16x8*>((AsB) + swz(wm + 48 + lr, ks * 64 + lg * 16)); \
      bf16x8 b0 = *reinterpret_cast<const bf16x8*>((BsB) + swz(wn + 0 + lr, ks * 64 + lg * 16));  \
      bf16x8 b1 = *reinterpret_cast<const bf16x8*>((BsB) + swz(wn + 16 + lr, ks * 64 + lg * 16)); \
      bf16x8 b2 = *reinterpret_cast<const bf16x8*>((BsB) + swz(wn + 32 + lr, ks * 64 + lg * 16)); \
      bf16x8 b3 = *reinterpret_cast<const bf16x8*>((BsB) + swz(wn + 48 + lr, ks * 64 + lg * 16)); \
      MM(0, 0, a0, b0); MM(0, 1, a0, b1); MM(0, 2, a0, b2); MM(0, 3, a0, b3);   \
      MM(1, 0, a1, b0); MM(1, 1, a1, b1); MM(1, 2, a1, b2); MM(1, 3, a1, b3);   \
      MM(2, 0, a2, b0); MM(2, 1, a2, b1); MM(2, 2, a2, b2); MM(2, 3, a2, b3);   \
      MM(3, 0, a3, b0); MM(3, 1, a3, b1); MM(3, 2, a3, b2); MM(3, 3, a3, b3);   \
    }                                                                           \
  } while (0)

// shared epilogue: acc -> LDS bf16 (stride 136) -> coalesced 16B stores
#define EPILOGUE(Cs)                                                            \
  do {                                                                          \
    _Pragma("unroll")                                                           \
    for (int j = 0; j < 4; ++j) {                                               \
      float bv = bias ? bias[col0 + wn + j * 16 + lr] : 0.f;                    \
      _Pragma("unroll")                                                         \
      for (int i = 0; i < 4; ++i)                                               \
        _Pragma("unroll")                                                       \
        for (int r = 0; r < 4; ++r) {                                           \
          float v = acc[i][j][r] + bv;                                          \
          if (RELU) v = fmaxf(v, 0.f);                                          \
          (Cs)[(wm + i * 16 + lg * 4 + r) * 136 + wn + j * 16 + lr] = f2bf(v);  \
        }                                                                       \
    }                                                                           \
    __syncthreads();                                                            \
    _Pragma("unroll")                                                           \
    for (int u = 0; u < 8; ++u) {                                               \
      int unit = tid + u * 256;                                                 \
      int r = unit >> 4, cg = unit & 15;                                        \
      int grow = row0 + r;                                                      \
      if (grow < M)                                                             \
        *reinterpret_cast<uint4*>(C + (size_t)grow * Nc + col0 + cg * 8) =      \
            *reinterpret_cast<const uint4*>((Cs) + r * 136 + cg * 8);           \
    }                                                                           \
  } while (0)

// ---------------------------------------------------------------------------
// GEMM, A fp32 with FUSED fp32->bf16: A reg-staged (coalesced float4 loads ->
// cvt_pk -> swizzled ds_write), B via global_load_lds. 128x128 tile, 4 waves,
// single-buffered 32KB LDS, 2 barriers/K-step. XCD-pinned col-blocks (id&7).
// ---------------------------------------------------------------------------
template<bool RELU, int NC>
__global__ __launch_bounds__(256, 3) void gemm_f32g(
    const float* __restrict__ A, const ushort* __restrict__ B,
    const float* __restrict__ bias, ushort* __restrict__ C,
    int M, int K, int Nc, int RB) {
  __shared__ char smem[128 * 136 * 2];  // 34816; staging uses first 32KB
  int rb, cb;
  {
    int id = blockIdx.x;
    int x = id & 7, g = id >> 3;
    cb = g % NC;
    rb = (g / NC) * 8 + x;
  }
  if (rb >= RB) return;
  const int row0 = rb * 128, col0 = cb * 128;
  const int tid = threadIdx.x, wid = tid >> 6, lane = tid & 63;
  const int lr = lane & 15, lg = lane >> 4;
  const int wm = (wid >> 1) * 64, wn = (wid & 1) * 64;
  char* AsB = smem;
  char* BsB = smem + 16384;

  f32x4 acc[4][4] = {};
  for (int kt = 0; kt < K; kt += 64) {
    STAGEB(BsB, B, col0, kt, K);
    // A: 128 rows x 4 chunks of 16 fp32; 512 units over 2 passes
#pragma unroll
    for (int u = 0; u < 2; ++u) {
      int unit = u * 256 + tid;
      int row = unit >> 2, chunk = unit & 3;
      if (row0 + row < M) {
        const float* p = A + (size_t)(row0 + row) * K + kt + chunk * 16;
        float4 f0 = *reinterpret_cast<const float4*>(p);
        float4 f1 = *reinterpret_cast<const float4*>(p + 4);
        float4 f2 = *reinterpret_cast<const float4*>(p + 8);
        float4 f3 = *reinterpret_cast<const float4*>(p + 12);
        uint4 w0, w1;
        w0.x = pkbf(f0.x, f0.y); w0.y = pkbf(f0.z, f0.w);
        w0.z = pkbf(f1.x, f1.y); w0.w = pkbf(f1.z, f1.w);
        w1.x = pkbf(f2.x, f2.y); w1.y = pkbf(f2.z, f2.w);
        w1.z = pkbf(f3.x, f3.y); w1.w = pkbf(f3.z, f3.w);
        *reinterpret_cast<uint4*>(AsB + swz(row, chunk * 32)) = w0;
        *reinterpret_cast<uint4*>(AsB + swz(row, chunk * 32 + 16)) = w1;
      }
    }
    __syncthreads();
    MFMABLOCK(AsB, BsB);
    __syncthreads();
  }
  ushort* Cs = reinterpret_cast<ushort*>(smem);
  EPILOGUE(Cs);
}

// ---------------------------------------------------------------------------
// bf16 GEMM: both A and B staged via global_load_lds (R9 structure).
// ---------------------------------------------------------------------------
template<bool RELU, int NC>
__global__ __launch_bounds__(256, 3) void gemm_glds(
    const ushort* __restrict__ A, const ushort* __restrict__ B,
    const float* __restrict__ bias, ushort* __restrict__ C,
    int M, int K, int Nc, int RB) {
  __shared__ char smem[128 * 136 * 2];
  int rb, cb;
  if (NC == 1) {
    rb = blockIdx.x; cb = 0;
  } else {
    int id = blockIdx.x;
    int x = id & 7, g = id >> 3;
    cb = g % NC;
    rb = (g / NC) * 8 + x;
  }
  if (rb >= RB) return;
  const int row0 = rb * 128, col0 = cb * 128;
  const int tid = threadIdx.x, wid = tid >> 6, lane = tid & 63;
  const int lr = lane & 15, lg = lane >> 4;
  const int wm = (wid >> 1) * 64, wn = (wid & 1) * 64;
  char* AsB = smem;
  char* BsB = smem + 16384;
  const int mrows = (M - row0 < 128) ? (M - row0) : 128;

#define STAGEA_G(buf, kt)                                                       \
  do {                                                                          \
    _Pragma("unroll")                                                           \
    for (int u = 0; u < 4; ++u) {                                               \
      int unit = u * 256 + tid;                                                 \
      int drow = unit >> 3, dkg = unit & 7;                                     \
      const ushort* src = A + (size_t)(row0 + drow) * K + (kt) +                \
                          (((dkg * 16) ^ ((drow & 7) << 4)) >> 1);              \
      if (drow < mrows)                                                         \
        __builtin_amdgcn_global_load_lds(src, (buf) + u * 4096 + wid * 1024,    \
                                         16, 0, 0);                             \
    }                                                                           \
  } while (0)

  f32x4 acc[4][4] = {};
  for (int kt = 0; kt < K; kt += 64) {
    STAGEA_G(AsB, kt);
    STAGEB(BsB, B, col0, kt, K);
    __syncthreads();
    MFMABLOCK(AsB, BsB);
    __syncthreads();
  }
#undef STAGEA_G
  ushort* Cs = reinterpret_cast<ushort*>(smem);
  EPILOGUE(Cs);
}

// x fp32 + xb16 bf16 dual-write; x[:,0:128]=cat_emb, x[:,128:256]=LN(v2)
__global__ __launch_bounds__(256) void ln_concat(const ushort* __restrict__ v2,
    const float* __restrict__ g, const float* __restrict__ b,
    const int* __restrict__ cat_ids, const float* __restrict__ cat_table,
    float* __restrict__ x, ushort* __restrict__ xb16) {
  int w = (blockIdx.x * blockDim.x + threadIdx.x) >> 6;
  int lane = threadIdx.x & 63;
  if (w >= NN) return;
  unsigned raw = *reinterpret_cast<const unsigned*>(v2 + (size_t)w * 128 + lane * 2);
  float ax = __uint_as_float(raw << 16);
  float ay = __uint_as_float(raw & 0xFFFF0000u);
  float s = ax + ay, s2 = ax * ax + ay * ay;
  s = warp_sum(s); s2 = warp_sum(s2);
  float mu = s * (1.f / 128.f);
  float var = s2 * (1.f / 128.f) - mu * mu;
  float rs = rsqrtf(var + 1e-5f);
  float2 gg = *reinterpret_cast<const float2*>(g + lane * 2);
  float2 bb = *reinterpret_cast<const float2*>(b + lane * 2);
  float2 o;
  o.x = (ax - mu) * rs * gg.x + bb.x;
  o.y = (ay - mu) * rs * gg.y + bb.y;
  *reinterpret_cast<float2*>(x + (size_t)w * 256 + 128 + lane * 2) = o;
  *reinterpret_cast<unsigned*>(xb16 + (size_t)w * 256 + 128 + lane * 2) = pkbf(o.x, o.y);
  int cid = cat_ids[w];
  float2 ce = *reinterpret_cast<const float2*>(cat_table + (size_t)cid * 128 + lane * 2);
  *reinterpret_cast<float2*>(x + (size_t)w * 256 + lane * 2) = ce;
  *reinterpret_cast<unsigned*>(xb16 + (size_t)w * 256 + lane * 2) = pkbf(ce.x, ce.y);
}

// fused GAT: scores + 8x8 softmax + aggregate + bias + elu + residual + LN.
template<int H>
__global__ __launch_bounds__(256) void gat_fused(const ushort* __restrict__ h,
    const float* __restrict__ asv, const float* __restrict__ adv,
    const float* __restrict__ bias, const float* __restrict__ lng,
    const float* __restrict__ lnb, float* __restrict__ x,
    ushort* __restrict__ xb16) {
  constexpr int C = 256 / H;
  constexpr int GROUP = C / 4;
  __shared__ __align__(16) float hs[4][8][256];
  __shared__ float attS[4][8][H], attD[4][8][H];
  const int wid = threadIdx.x >> 6, lane = threadIdx.x & 63;
  const int g = blockIdx.x * 4 + wid;
  const int base = g * 8;
  const int hd = lane / GROUP;
  float4 as4 = *reinterpret_cast<const float4*>(asv + lane * 4);
  float4 ad4 = *reinterpret_cast<const float4*>(adv + lane * 4);
#pragma unroll
  for (int i = 0; i < 8; ++i) {
    uint2 raw = *reinterpret_cast<const uint2*>(h + (size_t)(base + i) * 256 + lane * 4);
    float f0 = __uint_as_float(raw.x << 16);
    float f1 = __uint_as_float(raw.x & 0xFFFF0000u);
    float f2 = __uint_as_float(raw.y << 16);
    float f3 = __uint_as_float(raw.y & 0xFFFF0000u);
    *reinterpret_cast<float4*>(&hs[wid][i][lane * 4]) = make_float4(f0, f1, f2, f3);
    float ps = f0 * as4.x + f1 * as4.y + f2 * as4.z + f3 * as4.w;
    float pd = f0 * ad4.x + f1 * ad4.y + f2 * ad4.z + f3 * ad4.w;
#pragma unroll
    for (int o = GROUP / 2; o >= 1; o >>= 1) {
      ps += __shfl_xor(ps, o);
      pd += __shfl_xor(pd, o);
    }
    if ((lane & (GROUP - 1)) == 0) {
      attS[wid][i][hd] = ps;
      attD[wid][i][hd] = pd;
    }
  }
  __syncthreads();
  const float4 gv = *reinterpret_cast<const float4*>(lng + lane * 4);
  const float4 bv = *reinterpret_cast<const float4*>(lnb + lane * 4);
  const float4 biasv = *reinterpret_cast<const float4*>(bias + lane * 4);
  for (int i = 0; i < 8; ++i) {
    float ad = attD[wid][i][hd];
    float e[8];
    float mx = -1e30f;
#pragma unroll
    for (int j = 0; j < 8; ++j) {
      float v = attS[wid][j][hd] + ad;
      v = v > 0.f ? v : 0.2f * v;
      e[j] = v;
      mx = fmaxf(mx, v);
    }
    float sum = 0.f;
#pragma unroll
    for (int j = 0; j < 8; ++j) { e[j] = expf(e[j] - mx); sum += e[j]; }
    float inv = 1.f / (sum + 1e-16f);
    float a0 = 0, a1 = 0, a2 = 0, a3 = 0;
#pragma unroll
    for (int j = 0; j < 8; ++j) {
      float wj = e[j] * inv;
      float4 hv = *reinterpret_cast<const float4*>(&hs[wid][j][lane * 4]);
      a0 += wj * hv.x; a1 += wj * hv.y; a2 += wj * hv.z; a3 += wj * hv.w;
    }
    float4 xr = *reinterpret_cast<const float4*>(x + (size_t)(base + i) * 256 + lane * 4);
    float v0 = elu_f(a0 + biasv.x) + xr.x;
    float v1 = elu_f(a1 + biasv.y) + xr.y;
    float v2 = elu_f(a2 + biasv.z) + xr.z;
    float v3 = elu_f(a3 + biasv.w) + xr.w;
    float s = v0 + v1 + v2 + v3;
    float s2 = v0 * v0 + v1 * v1 + v2 * v2 + v3 * v3;
    s = warp_sum(s); s2 = warp_sum(s2);
    float mu = s * (1.f / 256.f);
    float var = s2 * (1.f / 256.f) - mu * mu;
    float rs = rsqrtf(var + 1e-5f);
    float4 o;
    o.x = (v0 - mu) * rs * gv.x + bv.x;
    o.y = (v1 - mu) * rs * gv.y + bv.y;
    o.z = (v2 - mu) * rs * gv.z + bv.z;
    o.w = (v3 - mu) * rs * gv.w + bv.w;
    *reinterpret_cast<float4*>(x + (size_t)(base + i) * 256 + lane * 4) = o;
    uint2 ob;
    ob.x = pkbf(o.x, o.y);
    ob.y = pkbf(o.z, o.w);
    *reinterpret_cast<uint2*>(xb16 + (size_t)(base + i) * 256 + lane * 4) = ob;
  }
}

__global__ __launch_bounds__(256) void pool_readout(const float* __restrict__ x,
    const float* __restrict__ rw, const float* __restrict__ rb,
    float* __restrict__ out) {
  int g = (blockIdx.x * blockDim.x + threadIdx.x) >> 6;
  int lane = threadIdx.x & 63;
  if (g >= NG) return;
  float a0 = 0, a1 = 0, a2 = 0, a3 = 0;
#pragma unroll
  for (int j = 0; j < 8; ++j) {
    float4 v = *reinterpret_cast<const float4*>(x + (size_t)(g * 8 + j) * 256 + lane * 4);
    a0 += v.x; a1 += v.y; a2 += v.z; a3 += v.w;
  }
  float4 w = *reinterpret_cast<const float4*>(rw + lane * 4);
  float p = (a0 * w.x + a1 * w.y + a2 * w.z + a3 * w.w) * 0.125f;
  p = warp_sum(p);
  if (lane == 0) out[g] = 1.f / (1.f + expf(-(p + rb[0])));
}

extern "C" void kernel_launch(void* const* d_in, const int* in_sizes, int n_in,
                              void* d_out, int out_size, void* d_ws, size_t ws_size,
                              hipStream_t stream) {
  const int* cat_ids = (const int*)d_in[0];
  const float* vf = (const float*)d_in[1];
  const float* cat_table = (const float*)d_in[4];
  const float* vp_w1 = (const float*)d_in[5];
  const float* vp_b1 = (const float*)d_in[6];
  const float* vp_w2 = (const float*)d_in[7];
  const float* vp_b2 = (const float*)d_in[8];
  const float* vp_lng = (const float*)d_in[9];
  const float* vp_lnb = (const float*)d_in[10];
  const float* c0_w = (const float*)d_in[11];
  const float* c0_as = (const float*)d_in[12];
  const float* c0_ad = (const float*)d_in[13];
  const float* c0_b = (const float*)d_in[14];
  const float* ln0_g = (const float*)d_in[15];
  const float* ln0_b = (const float*)d_in[16];
  const float* c1_w = (const float*)d_in[17];
  const float* c1_as = (const float*)d_in[18];
  const float* c1_ad = (const float*)d_in[19];
  const float* c1_b = (const float*)d_in[20];
  const float* ln1_g = (const float*)d_in[21];
  const float* ln1_b = (const float*)d_in[22];
  const float* ro_w = (const float*)d_in[23];
  const float* ro_b = (const float*)d_in[24];
  float* out = (float*)d_out;

  char* ws = (char*)d_ws;
  ushort* w1b = (ushort*)ws;   ws += (size_t)512 * 2048 * 2;
  ushort* w2b = (ushort*)ws;   ws += (size_t)128 * 512 * 2;
  ushort* c0wb = (ushort*)ws;  ws += (size_t)256 * 256 * 2;
  ushort* c1wb = (ushort*)ws;  ws += (size_t)256 * 256 * 2;
  ushort* v1b = (ushort*)ws;   ws += (size_t)NN * 512 * 2;
  ushort* v2b = (ushort*)ws;   ws += (size_t)NN * 128 * 2;
  float* xb = (float*)ws;      ws += (size_t)NN * 256 * 4;
  ushort* xbb = (ushort*)ws;   ws += (size_t)NN * 256 * 2;
  ushort* hbb = (ushort*)ws;

  dim3 b256(256);
  const int RB = (NN + 127) / 128;        // 782
  const int RBpad = ((RB + 7) / 8) * 8;   // 784

  cvt_bf16<<<1024, b256, 0, stream>>>(vp_w1, w1b, 512 * 2048 / 4);
  cvt_bf16<<<64, b256, 0, stream>>>(vp_w2, w2b, 128 * 512 / 4);
  cvt_bf16<<<64, b256, 0, stream>>>(c0_w, c0wb, 256 * 256 / 4);
  cvt_bf16<<<64, b256, 0, stream>>>(c1_w, c1wb, 256 * 256 / 4);

  // v1 = relu(vf @ w1^T + b1): fused fp32->bf16 staging, NC=4 XCD-pinned
  gemm_f32g<true, 4><<<RBpad * 4, b256, 0, stream>>>(vf, w1b, vp_b1, v1b,
                                                     NN, 2048, 512, RB);
  // v2 = v1 @ w2^T + b2
  gemm_glds<false, 1><<<RB, b256, 0, stream>>>(v1b, w2b, vp_b2, v2b,
                                               NN, 512, 128, RB);
  ln_concat<<<(NN * 64 + 255) / 256, b256, 0, stream>>>(v2b, vp_lng, vp_lnb,
                                                        cat_ids, cat_table, xb, xbb);

  gemm_glds<false, 2><<<RBpad * 2, b256, 0, stream>>>(xbb, c0wb, nullptr, hbb,
                                                      NN, 256, 256, RB);
  gat_fused<4><<<NG / 4, b256, 0, stream>>>(hbb, c0_as, c0_ad, c0_b, ln0_g, ln0_b, xb, xbb);

  gemm_glds<false, 2><<<RBpad * 2, b256, 0, stream>>>(xbb, c1wb, nullptr, hbb,
                                                      NN, 256, 256, RB);
  gat_fused<1><<<NG / 4, b256, 0, stream>>>(hbb, c1_as, c1_ad, c1_b, ln1_g, ln1_b, xb, xbb);

  pool_readout<<<NG / 4, b256, 0, stream>>>(xb, ro_w, ro_b, out);
}

// Round 11
// 631.002 us; speedup vs baseline: 2.4737x; 1.0690x over previous
//
#include <hip/hip_runtime.h>
#include <hip/hip_bf16.h>
#include <math.h>

#define NN 100000
#define NG 12500

using f32x4 = __attribute__((ext_vector_type(4))) float;
using bf16x8 = __attribute__((ext_vector_type(8))) __bf16;

__device__ __forceinline__ float warp_sum(float v) {
#pragma unroll
  for (int o = 32; o >= 1; o >>= 1) v += __shfl_xor(v, o);
  return v;
}

__device__ __forceinline__ float elu_f(float x) {
  return x > 0.f ? x : expm1f(x);
}

__device__ __forceinline__ ushort f2bf(float f) {
  unsigned u = __float_as_uint(f);
  u += 0x7FFFu + ((u >> 16) & 1u);
  return (ushort)(u >> 16);
}

// HW packed fp32->bf16 RNE: lo16 = bf16(a), hi16 = bf16(b)
__device__ __forceinline__ unsigned pkbf(float a, float b) {
  unsigned r;
  asm("v_cvt_pk_bf16_f32 %0, %1, %2" : "=v"(r) : "v"(a), "v"(b));
  return r;
}

// swizzled byte offset into a [row][64 bf16] LDS tile (row stride 128 B)
__device__ __forceinline__ int swz(int row, int kbyte) {
  return row * 128 + (kbyte ^ ((row & 7) << 4));
}

__global__ __launch_bounds__(256) void cvt_bf16(const float* __restrict__ src,
                                                ushort* __restrict__ dst, int n4) {
  int i = blockIdx.x * 256 + threadIdx.x;
  if (i >= n4) return;
  float4 v = *reinterpret_cast<const float4*>(src + (size_t)i * 4);
  ushort4 o;
  o.x = f2bf(v.x); o.y = f2bf(v.y); o.z = f2bf(v.z); o.w = f2bf(v.w);
  *reinterpret_cast<ushort4*>(dst + (size_t)i * 4) = o;
}

#define MM(i, j, a, b) \
  acc[i][j] = __builtin_amdgcn_mfma_f32_16x16x32_bf16(a, b, acc[i][j], 0, 0, 0)

// B staging via global_load_lds (pre-swizzled source, linear LDS dest)
#define STAGEB(buf, base, rowoff, kt, K)                                        \
  do {                                                                          \
    _Pragma("unroll")                                                           \
    for (int u = 0; u < 4; ++u) {                                               \
      int unit = u * 256 + tid;                                                 \
      int drow = unit >> 3, dkg = unit & 7;                                     \
      const ushort* src = (base) + (size_t)((rowoff) + drow) * (K) + (kt) +     \
                          (((dkg * 16) ^ ((drow & 7) << 4)) >> 1);              \
      __builtin_amdgcn_global_load_lds(src, (buf) + u * 4096 + wid * 1024,      \
                                       16, 0, 0);                               \
    }                                                                           \
  } while (0)

// MFMA inner block over one staged K-step (both A,B bf16 in LDS), 64x64/wave
#define MFMABLOCK(AsB, BsB)                                                     \
  do {                                                                          \
    _Pragma("unroll")                                                           \
    for (int ks = 0; ks < 2; ++ks) {                                            \
      bf16x8 a0 = *reinterpret_cast<const bf16x8*>((AsB) + swz(wm + 0 + lr, ks * 64 + lg * 16));  \
      bf16x8 a1 = *reinterpret_cast<const bf16x8*>((AsB) + swz(wm + 16 + lr, ks * 64 + lg * 16)); \
      bf16x8 a2 = *reinterpret_cast<const bf16x8*>((AsB) + swz(wm + 32 + lr, ks * 64 + lg * 16)); \
      bf16x8 a3 = *reinterpret_cast<const bf16x8*>((AsB) + swz(wm + 48 + lr, ks * 64 + lg * 16)); \
      bf16x8 b0 = *reinterpret_cast<const bf16x8*>((BsB) + swz(wn + 0 + lr, ks * 64 + lg * 16));  \
      bf16x8 b1 = *reinterpret_cast<const bf16x8*>((BsB) + swz(wn + 16 + lr, ks * 64 + lg * 16)); \
      bf16x8 b2 = *reinterpret_cast<const bf16x8*>((BsB) + swz(wn + 32 + lr, ks * 64 + lg * 16)); \
      bf16x8 b3 = *reinterpret_cast<const bf16x8*>((BsB) + swz(wn + 48 + lr, ks * 64 + lg * 16)); \
      MM(0, 0, a0, b0); MM(0, 1, a0, b1); MM(0, 2, a0, b2); MM(0, 3, a0, b3);   \
      MM(1, 0, a1, b0); MM(1, 1, a1, b1); MM(1, 2, a1, b2); MM(1, 3, a1, b3);   \
      MM(2, 0, a2, b0); MM(2, 1, a2, b1); MM(2, 2, a2, b2); MM(2, 3, a2, b3);   \
      MM(3, 0, a3, b0); MM(3, 1, a3, b1); MM(3, 2, a3, b2); MM(3, 3, a3, b3);   \
    }                                                                           \
  } while (0)

// shared epilogue for 128x128 tiles
#define EPILOGUE(Cs)                                                            \
  do {                                                                          \
    _Pragma("unroll")                                                           \
    for (int j = 0; j < 4; ++j) {                                               \
      float bv = bias ? bias[col0 + wn + j * 16 + lr] : 0.f;                    \
      _Pragma("unroll")                                                         \
      for (int i = 0; i < 4; ++i)                                               \
        _Pragma("unroll")                                                       \
        for (int r = 0; r < 4; ++r) {                                           \
          float v = acc[i][j][r] + bv;                                          \
          if (RELU) v = fmaxf(v, 0.f);                                          \
          (Cs)[(wm + i * 16 + lg * 4 + r) * 136 + wn + j * 16 + lr] = f2bf(v);  \
        }                                                                       \
    }                                                                           \
    __syncthreads();                                                            \
    _Pragma("unroll")                                                           \
    for (int u = 0; u < 8; ++u) {                                               \
      int unit = tid + u * 256;                                                 \
      int r = unit >> 4, cg = unit & 15;                                        \
      int grow = row0 + r;                                                      \
      if (grow < M)                                                             \
        *reinterpret_cast<uint4*>(C + (size_t)grow * Nc + col0 + cg * 8) =      \
            *reinterpret_cast<const uint4*>((Cs) + r * 136 + cg * 8);           \
    }                                                                           \
  } while (0)

// ---------------------------------------------------------------------------
// GEMM1: A fp32 with fused fp32->bf16, FULL-WIDTH BN=512 per block so A is
// read from HBM exactly once (no col-block L2 gamble). 64 rows x 512 cols,
// 4 waves each 64x128. B (2MB, globally hot) staged 64KB/K-step via glds.
// LDS 72KB -> 2 blocks/CU. 2 barriers/K-step.
// ---------------------------------------------------------------------------
template<bool RELU>
__global__ __launch_bounds__(256, 2) void gemm_f32w(
    const float* __restrict__ A, const ushort* __restrict__ B,
    const float* __restrict__ bias, ushort* __restrict__ C, int M, int K) {
  constexpr int BN = 512;
  __shared__ char smem[8192 + 65536];  // A 8KB + B 64KB; epilogue reuses
  const int row0 = blockIdx.x * 64;
  const int tid = threadIdx.x, wid = tid >> 6, lane = tid & 63;
  const int lr = lane & 15, lg = lane >> 4;
  const int wn = wid * 128;  // wave col offset
  char* AsB = smem;
  char* BsB = smem + 8192;
  const int arow = tid >> 2, achunk = tid & 3;
  const bool aval = (row0 + arow) < M;
  const float* Aprow = A + (size_t)(row0 + arow) * K + achunk * 16;
  const int awb0 = swz(arow, achunk * 32), awb1 = swz(arow, achunk * 32 + 16);

  f32x4 acc[4][8] = {};
  for (int kt = 0; kt < K; kt += 64) {
    // stage B: 512 rows x 8 kgroups = 4096 units of 16B
#pragma unroll
    for (int u = 0; u < 16; ++u) {
      int unit = u * 256 + tid;
      int drow = unit >> 3, dkg = unit & 7;
      const ushort* src = B + (size_t)drow * K + kt +
                          (((dkg * 16) ^ ((drow & 7) << 4)) >> 1);
      __builtin_amdgcn_global_load_lds(src, BsB + u * 4096 + wid * 1024, 16, 0, 0);
    }
    // stage A: 64 rows x 4 chunks of 16 fp32 = 256 units (1/thread)
    if (aval) {
      const float* p = Aprow + kt;
      float4 f0 = *reinterpret_cast<const float4*>(p);
      float4 f1 = *reinterpret_cast<const float4*>(p + 4);
      float4 f2 = *reinterpret_cast<const float4*>(p + 8);
      float4 f3 = *reinterpret_cast<const float4*>(p + 12);
      uint4 w0, w1;
      w0.x = pkbf(f0.x, f0.y); w0.y = pkbf(f0.z, f0.w);
      w0.z = pkbf(f1.x, f1.y); w0.w = pkbf(f1.z, f1.w);
      w1.x = pkbf(f2.x, f2.y); w1.y = pkbf(f2.z, f2.w);
      w1.z = pkbf(f3.x, f3.y); w1.w = pkbf(f3.z, f3.w);
      *reinterpret_cast<uint4*>(AsB + awb0) = w0;
      *reinterpret_cast<uint4*>(AsB + awb1) = w1;
    }
    __syncthreads();
#pragma unroll
    for (int ks = 0; ks < 2; ++ks) {
      bf16x8 a0 = *reinterpret_cast<const bf16x8*>(AsB + swz(0 + lr, ks * 64 + lg * 16));
      bf16x8 a1 = *reinterpret_cast<const bf16x8*>(AsB + swz(16 + lr, ks * 64 + lg * 16));
      bf16x8 a2 = *reinterpret_cast<const bf16x8*>(AsB + swz(32 + lr, ks * 64 + lg * 16));
      bf16x8 a3 = *reinterpret_cast<const bf16x8*>(AsB + swz(48 + lr, ks * 64 + lg * 16));
#pragma unroll
      for (int j = 0; j < 8; ++j) {
        bf16x8 bj = *reinterpret_cast<const bf16x8*>(BsB + swz(wn + j * 16 + lr, ks * 64 + lg * 16));
        MM(0, j, a0, bj); MM(1, j, a1, bj); MM(2, j, a2, bj); MM(3, j, a3, bj);
      }
    }
    __syncthreads();
  }
  // epilogue: 64 rows x 520-stride bf16 LDS tile -> coalesced stores
  ushort* Cs = reinterpret_cast<ushort*>(smem);
#pragma unroll
  for (int j = 0; j < 8; ++j) {
    float bv = bias[wn + j * 16 + lr];
#pragma unroll
    for (int i = 0; i < 4; ++i)
#pragma unroll
      for (int r = 0; r < 4; ++r) {
        float v = acc[i][j][r] + bv;
        if (RELU) v = fmaxf(v, 0.f);
        Cs[(i * 16 + lg * 4 + r) * 520 + wn + j * 16 + lr] = f2bf(v);
      }
  }
  __syncthreads();
#pragma unroll
  for (int u = 0; u < 16; ++u) {
    int unit = tid + u * 256;
    int r = unit >> 6, cg = unit & 63;  // 64 rows x 64 groups of 8
    int grow = row0 + r;
    if (grow < M)
      *reinterpret_cast<uint4*>(C + (size_t)grow * BN + cg * 8) =
          *reinterpret_cast<const uint4*>(Cs + r * 520 + cg * 8);
  }
}

// ---------------------------------------------------------------------------
// bf16 GEMM: both A and B staged via global_load_lds (R9 structure, 128x128).
// ---------------------------------------------------------------------------
template<bool RELU, int NC>
__global__ __launch_bounds__(256, 3) void gemm_glds(
    const ushort* __restrict__ A, const ushort* __restrict__ B,
    const float* __restrict__ bias, ushort* __restrict__ C,
    int M, int K, int Nc, int RB) {
  __shared__ char smem[128 * 136 * 2];
  int rb, cb;
  if (NC == 1) {
    rb = blockIdx.x; cb = 0;
  } else {
    int id = blockIdx.x;
    int x = id & 7, g = id >> 3;
    cb = g % NC;
    rb = (g / NC) * 8 + x;
  }
  if (rb >= RB) return;
  const int row0 = rb * 128, col0 = cb * 128;
  const int tid = threadIdx.x, wid = tid >> 6, lane = tid & 63;
  const int lr = lane & 15, lg = lane >> 4;
  const int wm = (wid >> 1) * 64, wn = (wid & 1) * 64;
  char* AsB = smem;
  char* BsB = smem + 16384;
  const int mrows = (M - row0 < 128) ? (M - row0) : 128;

#define STAGEA_G(buf, kt)                                                       \
  do {                                                                          \
    _Pragma("unroll")                                                           \
    for (int u = 0; u < 4; ++u) {                                               \
      int unit = u * 256 + tid;                                                 \
      int drow = unit >> 3, dkg = unit & 7;                                     \
      const ushort* src = A + (size_t)(row0 + drow) * K + (kt) +                \
                          (((dkg * 16) ^ ((drow & 7) << 4)) >> 1);              \
      if (drow < mrows)                                                         \
        __builtin_amdgcn_global_load_lds(src, (buf) + u * 4096 + wid * 1024,    \
                                         16, 0, 0);                             \
    }                                                                           \
  } while (0)

  f32x4 acc[4][4] = {};
  for (int kt = 0; kt < K; kt += 64) {
    STAGEA_G(AsB, kt);
    STAGEB(BsB, B, col0, kt, K);
    __syncthreads();
    MFMABLOCK(AsB, BsB);
    __syncthreads();
  }
#undef STAGEA_G
  ushort* Cs = reinterpret_cast<ushort*>(smem);
  EPILOGUE(Cs);
}

// x fp32 + xb16 bf16 dual-write; x[:,0:128]=cat_emb, x[:,128:256]=LN(v2)
__global__ __launch_bounds__(256) void ln_concat(const ushort* __restrict__ v2,
    const float* __restrict__ g, const float* __restrict__ b,
    const int* __restrict__ cat_ids, const float* __restrict__ cat_table,
    float* __restrict__ x, ushort* __restrict__ xb16) {
  int w = (blockIdx.x * blockDim.x + threadIdx.x) >> 6;
  int lane = threadIdx.x & 63;
  if (w >= NN) return;
  unsigned raw = *reinterpret_cast<const unsigned*>(v2 + (size_t)w * 128 + lane * 2);
  float ax = __uint_as_float(raw << 16);
  float ay = __uint_as_float(raw & 0xFFFF0000u);
  float s = ax + ay, s2 = ax * ax + ay * ay;
  s = warp_sum(s); s2 = warp_sum(s2);
  float mu = s * (1.f / 128.f);
  float var = s2 * (1.f / 128.f) - mu * mu;
  float rs = rsqrtf(var + 1e-5f);
  float2 gg = *reinterpret_cast<const float2*>(g + lane * 2);
  float2 bb = *reinterpret_cast<const float2*>(b + lane * 2);
  float2 o;
  o.x = (ax - mu) * rs * gg.x + bb.x;
  o.y = (ay - mu) * rs * gg.y + bb.y;
  *reinterpret_cast<float2*>(x + (size_t)w * 256 + 128 + lane * 2) = o;
  *reinterpret_cast<unsigned*>(xb16 + (size_t)w * 256 + 128 + lane * 2) = pkbf(o.x, o.y);
  int cid = cat_ids[w];
  float2 ce = *reinterpret_cast<const float2*>(cat_table + (size_t)cid * 128 + lane * 2);
  *reinterpret_cast<float2*>(x + (size_t)w * 256 + lane * 2) = ce;
  *reinterpret_cast<unsigned*>(xb16 + (size_t)w * 256 + lane * 2) = pkbf(ce.x, ce.y);
}

// fused GAT: scores + 8x8 softmax + aggregate + bias + elu + residual + LN.
template<int H>
__global__ __launch_bounds__(256) void gat_fused(const ushort* __restrict__ h,
    const float* __restrict__ asv, const float* __restrict__ adv,
    const float* __restrict__ bias, const float* __restrict__ lng,
    const float* __restrict__ lnb, float* __restrict__ x,
    ushort* __restrict__ xb16) {
  constexpr int C = 256 / H;
  constexpr int GROUP = C / 4;
  __shared__ __align__(16) float hs[4][8][256];
  __shared__ float attS[4][8][H], attD[4][8][H];
  const int wid = threadIdx.x >> 6, lane = threadIdx.x & 63;
  const int g = blockIdx.x * 4 + wid;
  const int base = g * 8;
  const int hd = lane / GROUP;
  float4 as4 = *reinterpret_cast<const float4*>(asv + lane * 4);
  float4 ad4 = *reinterpret_cast<const float4*>(adv + lane * 4);
#pragma unroll
  for (int i = 0; i < 8; ++i) {
    uint2 raw = *reinterpret_cast<const uint2*>(h + (size_t)(base + i) * 256 + lane * 4);
    float f0 = __uint_as_float(raw.x << 16);
    float f1 = __uint_as_float(raw.x & 0xFFFF0000u);
    float f2 = __uint_as_float(raw.y << 16);
    float f3 = __uint_as_float(raw.y & 0xFFFF0000u);
    *reinterpret_cast<float4*>(&hs[wid][i][lane * 4]) = make_float4(f0, f1, f2, f3);
    float ps = f0 * as4.x + f1 * as4.y + f2 * as4.z + f3 * as4.w;
    float pd = f0 * ad4.x + f1 * ad4.y + f2 * ad4.z + f3 * ad4.w;
#pragma unroll
    for (int o = GROUP / 2; o >= 1; o >>= 1) {
      ps += __shfl_xor(ps, o);
      pd += __shfl_xor(pd, o);
    }
    if ((lane & (GROUP - 1)) == 0) {
      attS[wid][i][hd] = ps;
      attD[wid][i][hd] = pd;
    }
  }
  __syncthreads();
  const float4 gv = *reinterpret_cast<const float4*>(lng + lane * 4);
  const float4 bv = *reinterpret_cast<const float4*>(lnb + lane * 4);
  const float4 biasv = *reinterpret_cast<const float4*>(bias + lane * 4);
  for (int i = 0; i < 8; ++i) {
    float ad = attD[wid][i][hd];
    float e[8];
    float mx = -1e30f;
#pragma unroll
    for (int j = 0; j < 8; ++j) {
      float v = attS[wid][j][hd] + ad;
      v = v > 0.f ? v : 0.2f * v;
      e[j] = v;
      mx = fmaxf(mx, v);
    }
    float sum = 0.f;
#pragma unroll
    for (int j = 0; j < 8; ++j) { e[j] = expf(e[j] - mx); sum += e[j]; }
    float inv = 1.f / (sum + 1e-16f);
    float a0 = 0, a1 = 0, a2 = 0, a3 = 0;
#pragma unroll
    for (int j = 0; j < 8; ++j) {
      float wj = e[j] * inv;
      float4 hv = *reinterpret_cast<const float4*>(&hs[wid][j][lane * 4]);
      a0 += wj * hv.x; a1 += wj * hv.y; a2 += wj * hv.z; a3 += wj * hv.w;
    }
    float4 xr = *reinterpret_cast<const float4*>(x + (size_t)(base + i) * 256 + lane * 4);
    float v0 = elu_f(a0 + biasv.x) + xr.x;
    float v1 = elu_f(a1 + biasv.y) + xr.y;
    float v2 = elu_f(a2 + biasv.z) + xr.z;
    float v3 = elu_f(a3 + biasv.w) + xr.w;
    float s = v0 + v1 + v2 + v3;
    float s2 = v0 * v0 + v1 * v1 + v2 * v2 + v3 * v3;
    s = warp_sum(s); s2 = warp_sum(s2);
    float mu = s * (1.f / 256.f);
    float var = s2 * (1.f / 256.f) - mu * mu;
    float rs = rsqrtf(var + 1e-5f);
    float4 o;
    o.x = (v0 - mu) * rs * gv.x + bv.x;
    o.y = (v1 - mu) * rs * gv.y + bv.y;
    o.z = (v2 - mu) * rs * gv.z + bv.z;
    o.w = (v3 - mu) * rs * gv.w + bv.w;
    *reinterpret_cast<float4*>(x + (size_t)(base + i) * 256 + lane * 4) = o;
    uint2 ob;
    ob.x = pkbf(o.x, o.y);
    ob.y = pkbf(o.z, o.w);
    *reinterpret_cast<uint2*>(xb16 + (size_t)(base + i) * 256 + lane * 4) = ob;
  }
}

__global__ __launch_bounds__(256) void pool_readout(const float* __restrict__ x,
    const float* __restrict__ rw, const float* __restrict__ rb,
    float* __restrict__ out) {
  int g = (blockIdx.x * blockDim.x + threadIdx.x) >> 6;
  int lane = threadIdx.x & 63;
  if (g >= NG) return;
  float a0 = 0, a1 = 0, a2 = 0, a3 = 0;
#pragma unroll
  for (int j = 0; j < 8; ++j) {
    float4 v = *reinterpret_cast<const float4*>(x + (size_t)(g * 8 + j) * 256 + lane * 4);
    a0 += v.x; a1 += v.y; a2 += v.z; a3 += v.w;
  }
  float4 w = *reinterpret_cast<const float4*>(rw + lane * 4);
  float p = (a0 * w.x + a1 * w.y + a2 * w.z + a3 * w.w) * 0.125f;
  p = warp_sum(p);
  if (lane == 0) out[g] = 1.f / (1.f + expf(-(p + rb[0])));
}

extern "C" void kernel_launch(void* const* d_in, const int* in_sizes, int n_in,
                              void* d_out, int out_size, void* d_ws, size_t ws_size,
                              hipStream_t stream) {
  const int* cat_ids = (const int*)d_in[0];
  const float* vf = (const float*)d_in[1];
  const float* cat_table = (const float*)d_in[4];
  const float* vp_w1 = (const float*)d_in[5];
  const float* vp_b1 = (const float*)d_in[6];
  const float* vp_w2 = (const float*)d_in[7];
  const float* vp_b2 = (const float*)d_in[8];
  const float* vp_lng = (const float*)d_in[9];
  const float* vp_lnb = (const float*)d_in[10];
  const float* c0_w = (const float*)d_in[11];
  const float* c0_as = (const float*)d_in[12];
  const float* c0_ad = (const float*)d_in[13];
  const float* c0_b = (const float*)d_in[14];
  const float* ln0_g = (const float*)d_in[15];
  const float* ln0_b = (const float*)d_in[16];
  const float* c1_w = (const float*)d_in[17];
  const float* c1_as = (const float*)d_in[18];
  const float* c1_ad = (const float*)d_in[19];
  const float* c1_b = (const float*)d_in[20];
  const float* ln1_g = (const float*)d_in[21];
  const float* ln1_b = (const float*)d_in[22];
  const float* ro_w = (const float*)d_in[23];
  const float* ro_b = (const float*)d_in[24];
  float* out = (float*)d_out;

  char* ws = (char*)d_ws;
  ushort* w1b = (ushort*)ws;   ws += (size_t)512 * 2048 * 2;
  ushort* w2b = (ushort*)ws;   ws += (size_t)128 * 512 * 2;
  ushort* c0wb = (ushort*)ws;  ws += (size_t)256 * 256 * 2;
  ushort* c1wb = (ushort*)ws;  ws += (size_t)256 * 256 * 2;
  ushort* v1b = (ushort*)ws;   ws += (size_t)NN * 512 * 2;
  ushort* v2b = (ushort*)ws;   ws += (size_t)NN * 128 * 2;
  float* xb = (float*)ws;      ws += (size_t)NN * 256 * 4;
  ushort* xbb = (ushort*)ws;   ws += (size_t)NN * 256 * 2;
  ushort* hbb = (ushort*)ws;

  dim3 b256(256);
  const int RB64 = (NN + 63) / 64;        // 1563
  const int RB = (NN + 127) / 128;        // 782
  const int RBpad = ((RB + 7) / 8) * 8;   // 784

  cvt_bf16<<<1024, b256, 0, stream>>>(vp_w1, w1b, 512 * 2048 / 4);
  cvt_bf16<<<64, b256, 0, stream>>>(vp_w2, w2b, 128 * 512 / 4);
  cvt_bf16<<<64, b256, 0, stream>>>(c0_w, c0wb, 256 * 256 / 4);
  cvt_bf16<<<64, b256, 0, stream>>>(c1_w, c1wb, 256 * 256 / 4);

  // v1 = relu(vf @ w1^T + b1): full-width 64x512 blocks, A read once
  gemm_f32w<true><<<RB64, b256, 0, stream>>>(vf, w1b, vp_b1, v1b, NN, 2048);
  // v2 = v1 @ w2^T + b2
  gemm_glds<false, 1><<<RB, b256, 0, stream>>>(v1b, w2b, vp_b2, v2b,
                                               NN, 512, 128, RB);
  ln_concat<<<(NN * 64 + 255) / 256, b256, 0, stream>>>(v2b, vp_lng, vp_lnb,
                                                        cat_ids, cat_table, xb, xbb);

  gemm_glds<false, 2><<<RBpad * 2, b256, 0, stream>>>(xbb, c0wb, nullptr, hbb,
                                                      NN, 256, 256, RB);
  gat_fused<4><<<NG / 4, b256, 0, stream>>>(hbb, c0_as, c0_ad, c0_b, ln0_g, ln0_b, xb, xbb);

  gemm_glds<false, 2><<<RBpad * 2, b256, 0, stream>>>(xbb, c1wb, nullptr, hbb,
                                                      NN, 256, 256, RB);
  gat_fused<1><<<NG / 4, b256, 0, stream>>>(hbb, c1_as, c1_ad, c1_b, ln1_g, ln1_b, xb, xbb);

  pool_readout<<<NG / 4, b256, 0, stream>>>(xb, ro_w, ro_b, out);
}

// Round 13
// 619.872 us; speedup vs baseline: 2.5181x; 1.0180x over previous
//
#include <hip/hip_runtime.h>
#include <hip/hip_bf16.h>
#include <math.h>

#define NN 100000
#define NG 12500

using f32x4 = __attribute__((ext_vector_type(4))) float;
using bf16x8 = __attribute__((ext_vector_type(8))) __bf16;

__device__ __forceinline__ float warp_sum(float v) {
#pragma unroll
  for (int o = 32; o >= 1; o >>= 1) v += __shfl_xor(v, o);
  return v;
}

__device__ __forceinline__ float elu_f(float x) {
  return x > 0.f ? x : expm1f(x);
}

__device__ __forceinline__ ushort f2bf(float f) {
  unsigned u = __float_as_uint(f);
  u += 0x7FFFu + ((u >> 16) & 1u);
  return (ushort)(u >> 16);
}

// HW packed fp32->bf16 RNE: lo16 = bf16(a), hi16 = bf16(b)
__device__ __forceinline__ unsigned pkbf(float a, float b) {
  unsigned r;
  asm("v_cvt_pk_bf16_f32 %0, %1, %2" : "=v"(r) : "v"(a), "v"(b));
  return r;
}

// swizzled byte offset into a [row][64 bf16] LDS tile (row stride 128 B)
__device__ __forceinline__ int swz(int row, int kbyte) {
  return row * 128 + (kbyte ^ ((row & 7) << 4));
}

__global__ __launch_bounds__(256) void cvt_bf16(const float* __restrict__ src,
                                                ushort* __restrict__ dst, int n4) {
  int i = blockIdx.x * 256 + threadIdx.x;
  if (i >= n4) return;
  float4 v = *reinterpret_cast<const float4*>(src + (size_t)i * 4);
  ushort4 o;
  o.x = f2bf(v.x); o.y = f2bf(v.y); o.z = f2bf(v.z); o.w = f2bf(v.w);
  *reinterpret_cast<ushort4*>(dst + (size_t)i * 4) = o;
}

#define MM(i, j, a, b) \
  acc[i][j] = __builtin_amdgcn_mfma_f32_16x16x32_bf16(a, b, acc[i][j], 0, 0, 0)

// B staging via global_load_lds (pre-swizzled source, linear LDS dest), 256thr
#define STAGEB(buf, base, rowoff, kt, K)                                        \
  do {                                                                          \
    _Pragma("unroll")                                                           \
    for (int u = 0; u < 4; ++u) {                                               \
      int unit = u * 256 + tid;                                                 \
      int drow = unit >> 3, dkg = unit & 7;                                     \
      const ushort* src = (base) + (size_t)((rowoff) + drow) * (K) + (kt) +     \
                          (((dkg * 16) ^ ((drow & 7) << 4)) >> 1);              \
      __builtin_amdgcn_global_load_lds(src, (buf) + u * 4096 + wid * 1024,      \
                                       16, 0, 0);                               \
    }                                                                           \
  } while (0)

// MFMA inner block over one staged K-step (both A,B bf16 in LDS), 64x64/wave
#define MFMABLOCK(AsB, BsB)                                                     \
  do {                                                                          \
    _Pragma("unroll")                                                           \
    for (int ks = 0; ks < 2; ++ks) {                                            \
      bf16x8 a0 = *reinterpret_cast<const bf16x8*>((AsB) + swz(wm + 0 + lr, ks * 64 + lg * 16));  \
      bf16x8 a1 = *reinterpret_cast<const bf16x8*>((AsB) + swz(wm + 16 + lr, ks * 64 + lg * 16)); \
      bf16x8 a2 = *reinterpret_cast<const bf16x8*>((AsB) + swz(wm + 32 + lr, ks * 64 + lg * 16)); \
      bf16x8 a3 = *reinterpret_cast<const bf16x8*>((AsB) + swz(wm + 48 + lr, ks * 64 + lg * 16)); \
      bf16x8 b0 = *reinterpret_cast<const bf16x8*>((BsB) + swz(wn + 0 + lr, ks * 64 + lg * 16));  \
      bf16x8 b1 = *reinterpret_cast<const bf16x8*>((BsB) + swz(wn + 16 + lr, ks * 64 + lg * 16)); \
      bf16x8 b2 = *reinterpret_cast<const bf16x8*>((BsB) + swz(wn + 32 + lr, ks * 64 + lg * 16)); \
      bf16x8 b3 = *reinterpret_cast<const bf16x8*>((BsB) + swz(wn + 48 + lr, ks * 64 + lg * 16)); \
      MM(0, 0, a0, b0); MM(0, 1, a0, b1); MM(0, 2, a0, b2); MM(0, 3, a0, b3);   \
      MM(1, 0, a1, b0); MM(1, 1, a1, b1); MM(1, 2, a1, b2); MM(1, 3, a1, b3);   \
      MM(2, 0, a2, b0); MM(2, 1, a2, b1); MM(2, 2, a2, b2); MM(2, 3, a2, b3);   \
      MM(3, 0, a3, b0); MM(3, 1, a3, b1); MM(3, 2, a3, b2); MM(3, 3, a3, b3);   \
    }                                                                           \
  } while (0)

// shared epilogue for 128x128 tiles (256 thr)
#define EPILOGUE(Cs)                                                            \
  do {                                                                          \
    _Pragma("unroll")                                                           \
    for (int j = 0; j < 4; ++j) {                                               \
      float bv = bias ? bias[col0 + wn + j * 16 + lr] : 0.f;                    \
      _Pragma("unroll")                                                         \
      for (int i = 0; i < 4; ++i)                                               \
        _Pragma("unroll")                                                       \
        for (int r = 0; r < 4; ++r) {                                           \
          float v = acc[i][j][r] + bv;                                          \
          if (RELU) v = fmaxf(v, 0.f);                                          \
          (Cs)[(wm + i * 16 + lg * 4 + r) * 136 + wn + j * 16 + lr] = f2bf(v);  \
        }                                                                       \
    }                                                                           \
    __syncthreads();                                                            \
    _Pragma("unroll")                                                           \
    for (int u = 0; u < 8; ++u) {                                               \
      int unit = tid + u * 256;                                                 \
      int r = unit >> 4, cg = unit & 15;                                        \
      int grow = row0 + r;                                                      \
      if (grow < M)                                                             \
        *reinterpret_cast<uint4*>(C + (size_t)grow * Nc + col0 + cg * 8) =      \
            *reinterpret_cast<const uint4*>((Cs) + r * 136 + cg * 8);           \
    }                                                                           \
  } while (0)

// ---------------------------------------------------------------------------
// GEMM1: A fp32 fused-convert, BM=128 x BN=512 (full width: A read once,
// B-staging traffic halved vs BM=64). B DOUBLE-BUFFERED via glds with the
// vmcnt drain relocated AFTER the MFMA block (bar2), so B(t+1) latency hides
// under 64 MFMA. 512 thr = 8 waves (2 row x 4 col of 64x128). LDS 144KB ->
// 1 block/CU (2 waves/SIMD). NOTE: no LDS pointer ARRAYS (addrspacecast
// static-init bug, R12) - named Bs0/Bs1 + wave-uniform ternary.
// ---------------------------------------------------------------------------
template<bool RELU>
__global__ __launch_bounds__(512, 1) void gemm_f32p(
    const float* __restrict__ A, const ushort* __restrict__ B,
    const float* __restrict__ bias, ushort* __restrict__ C, int M, int K) {
  __shared__ char smem[16384 + 2 * 65536];  // A 16KB + B 64KB x2; epilogue reuse
  char* AsB = smem;
  char* Bs0 = smem + 16384;
  char* Bs1 = smem + 16384 + 65536;
  const int tid = threadIdx.x, wid = tid >> 6, lane = tid & 63;
  const int lr = lane & 15, lg = lane >> 4;
  const int wm = (wid >> 2) * 64;    // wave row offset (0/64)
  const int wn = (wid & 3) * 128;    // wave col offset (0..384)
  const int row0 = blockIdx.x * 128;
  const int arow = tid >> 2, achunk = tid & 3;
  const bool aval = (row0 + arow) < M;
  const float* Aprow = A + (size_t)(row0 + arow) * K + achunk * 16;
  const int awb0 = swz(arow, achunk * 32), awb1 = swz(arow, achunk * 32 + 16);

  float4 rA0, rA1, rA2, rA3;

#define LOADA_P(kt)                                                     \
  do {                                                                  \
    if (aval && (kt) < K) {                                             \
      const float* q = Aprow + (kt);                                    \
      rA0 = *reinterpret_cast<const float4*>(q);                        \
      rA1 = *reinterpret_cast<const float4*>(q + 4);                    \
      rA2 = *reinterpret_cast<const float4*>(q + 8);                    \
      rA3 = *reinterpret_cast<const float4*>(q + 12);                   \
    }                                                                   \
  } while (0)

#define ISSUEB_P(buf, kt)                                               \
  do {                                                                  \
    _Pragma("unroll")                                                   \
    for (int u = 0; u < 8; ++u) {                                       \
      int unit = u * 512 + tid;                                         \
      int drow = unit >> 3, dkg = unit & 7;                             \
      const ushort* src = B + (size_t)drow * K + (kt) +                 \
                          (((dkg * 16) ^ ((drow & 7) << 4)) >> 1);      \
      __builtin_amdgcn_global_load_lds(src, (buf) + u * 8192 + wid * 1024, \
                                       16, 0, 0);                       \
    }                                                                   \
  } while (0)

  f32x4 acc[4][8] = {};
  LOADA_P(0);
  ISSUEB_P(Bs0, 0);
  int cur = 0;
  for (int kt = 0; kt < K; kt += 64) {
    // write A(kt) from regs (loaded previous iter / prologue)
    if (aval) {
      uint4 w0, w1;
      w0.x = pkbf(rA0.x, rA0.y); w0.y = pkbf(rA0.z, rA0.w);
      w0.z = pkbf(rA1.x, rA1.y); w0.w = pkbf(rA1.z, rA1.w);
      w1.x = pkbf(rA2.x, rA2.y); w1.y = pkbf(rA2.z, rA2.w);
      w1.z = pkbf(rA3.x, rA3.y); w1.w = pkbf(rA3.z, rA3.w);
      *reinterpret_cast<uint4*>(AsB + awb0) = w0;
      *reinterpret_cast<uint4*>(AsB + awb1) = w1;
    }
    __syncthreads();  // bar1: B(kt) already drained at prev bar2; cheap
    char* BsB = cur ? Bs1 : Bs0;
    char* Bnxt = cur ? Bs0 : Bs1;
    if (kt + 64 < K) ISSUEB_P(Bnxt, kt + 64);
    LOADA_P(kt + 64);
    // 64 MFMA on current buffers
#pragma unroll
    for (int ks = 0; ks < 2; ++ks) {
      bf16x8 a0 = *reinterpret_cast<const bf16x8*>(AsB + swz(wm + 0 + lr, ks * 64 + lg * 16));
      bf16x8 a1 = *reinterpret_cast<const bf16x8*>(AsB + swz(wm + 16 + lr, ks * 64 + lg * 16));
      bf16x8 a2 = *reinterpret_cast<const bf16x8*>(AsB + swz(wm + 32 + lr, ks * 64 + lg * 16));
      bf16x8 a3 = *reinterpret_cast<const bf16x8*>(AsB + swz(wm + 48 + lr, ks * 64 + lg * 16));
#pragma unroll
      for (int j = 0; j < 8; ++j) {
        bf16x8 bj = *reinterpret_cast<const bf16x8*>(BsB + swz(wn + j * 16 + lr, ks * 64 + lg * 16));
        MM(0, j, a0, bj); MM(1, j, a1, bj); MM(2, j, a2, bj); MM(3, j, a3, bj);
      }
    }
    __syncthreads();  // bar2: drains B(kt+64)+A(kt+64) AFTER MFMA -> hidden
    cur ^= 1;
  }
#undef LOADA_P
#undef ISSUEB_P
  // epilogue: 128 rows x 520-stride bf16 tile -> coalesced stores
  ushort* Cs = reinterpret_cast<ushort*>(smem);
#pragma unroll
  for (int j = 0; j < 8; ++j) {
    float bv = bias[wn + j * 16 + lr];
#pragma unroll
    for (int i = 0; i < 4; ++i)
#pragma unroll
      for (int r = 0; r < 4; ++r) {
        float v = acc[i][j][r] + bv;
        if (RELU) v = fmaxf(v, 0.f);
        Cs[(wm + i * 16 + lg * 4 + r) * 520 + wn + j * 16 + lr] = f2bf(v);
      }
  }
  __syncthreads();
#pragma unroll
  for (int u = 0; u < 16; ++u) {
    int unit = tid + u * 512;
    int r = unit >> 6, cg = unit & 63;  // 128 rows x 64 groups of 8
    int grow = row0 + r;
    if (grow < M)
      *reinterpret_cast<uint4*>(C + (size_t)grow * 512 + cg * 8) =
          *reinterpret_cast<const uint4*>(Cs + r * 520 + cg * 8);
  }
}

// ---------------------------------------------------------------------------
// bf16 GEMM: both A and B staged via global_load_lds (R9 structure, 128x128).
// ---------------------------------------------------------------------------
template<bool RELU, int NC>
__global__ __launch_bounds__(256, 3) void gemm_glds(
    const ushort* __restrict__ A, const ushort* __restrict__ B,
    const float* __restrict__ bias, ushort* __restrict__ C,
    int M, int K, int Nc, int RB) {
  __shared__ char smem[128 * 136 * 2];
  int rb, cb;
  if (NC == 1) {
    rb = blockIdx.x; cb = 0;
  } else {
    int id = blockIdx.x;
    int x = id & 7, g = id >> 3;
    cb = g % NC;
    rb = (g / NC) * 8 + x;
  }
  if (rb >= RB) return;
  const int row0 = rb * 128, col0 = cb * 128;
  const int tid = threadIdx.x, wid = tid >> 6, lane = tid & 63;
  const int lr = lane & 15, lg = lane >> 4;
  const int wm = (wid >> 1) * 64, wn = (wid & 1) * 64;
  char* AsB = smem;
  char* BsB = smem + 16384;
  const int mrows = (M - row0 < 128) ? (M - row0) : 128;

#define STAGEA_G(buf, kt)                                                       \
  do {                                                                          \
    _Pragma("unroll")                                                           \
    for (int u = 0; u < 4; ++u) {                                               \
      int unit = u * 256 + tid;                                                 \
      int drow = unit >> 3, dkg = unit & 7;                                     \
      const ushort* src = A + (size_t)(row0 + drow) * K + (kt) +                \
                          (((dkg * 16) ^ ((drow & 7) << 4)) >> 1);              \
      if (drow < mrows)                                                         \
        __builtin_amdgcn_global_load_lds(src, (buf) + u * 4096 + wid * 1024,    \
                                         16, 0, 0);                             \
    }                                                                           \
  } while (0)

  f32x4 acc[4][4] = {};
  for (int kt = 0; kt < K; kt += 64) {
    STAGEA_G(AsB, kt);
    STAGEB(BsB, B, col0, kt, K);
    __syncthreads();
    MFMABLOCK(AsB, BsB);
    __syncthreads();
  }
#undef STAGEA_G
  ushort* Cs = reinterpret_cast<ushort*>(smem);
  EPILOGUE(Cs);
}

// x fp32 + xb16 bf16 dual-write; x[:,0:128]=cat_emb, x[:,128:256]=LN(v2)
__global__ __launch_bounds__(256) void ln_concat(const ushort* __restrict__ v2,
    const float* __restrict__ g, const float* __restrict__ b,
    const int* __restrict__ cat_ids, const float* __restrict__ cat_table,
    float* __restrict__ x, ushort* __restrict__ xb16) {
  int w = (blockIdx.x * blockDim.x + threadIdx.x) >> 6;
  int lane = threadIdx.x & 63;
  if (w >= NN) return;
  unsigned raw = *reinterpret_cast<const unsigned*>(v2 + (size_t)w * 128 + lane * 2);
  float ax = __uint_as_float(raw << 16);
  float ay = __uint_as_float(raw & 0xFFFF0000u);
  float s = ax + ay, s2 = ax * ax + ay * ay;
  s = warp_sum(s); s2 = warp_sum(s2);
  float mu = s * (1.f / 128.f);
  float var = s2 * (1.f / 128.f) - mu * mu;
  float rs = rsqrtf(var + 1e-5f);
  float2 gg = *reinterpret_cast<const float2*>(g + lane * 2);
  float2 bb = *reinterpret_cast<const float2*>(b + lane * 2);
  float2 o;
  o.x = (ax - mu) * rs * gg.x + bb.x;
  o.y = (ay - mu) * rs * gg.y + bb.y;
  *reinterpret_cast<float2*>(x + (size_t)w * 256 + 128 + lane * 2) = o;
  *reinterpret_cast<unsigned*>(xb16 + (size_t)w * 256 + 128 + lane * 2) = pkbf(o.x, o.y);
  int cid = cat_ids[w];
  float2 ce = *reinterpret_cast<const float2*>(cat_table + (size_t)cid * 128 + lane * 2);
  *reinterpret_cast<float2*>(x + (size_t)w * 256 + lane * 2) = ce;
  *reinterpret_cast<unsigned*>(xb16 + (size_t)w * 256 + lane * 2) = pkbf(ce.x, ce.y);
}

// fused GAT: scores + 8x8 softmax + aggregate + bias + elu + residual + LN.
template<int H>
__global__ __launch_bounds__(256) void gat_fused(const ushort* __restrict__ h,
    const float* __restrict__ asv, const float* __restrict__ adv,
    const float* __restrict__ bias, const float* __restrict__ lng,
    const float* __restrict__ lnb, float* __restrict__ x,
    ushort* __restrict__ xb16) {
  constexpr int C = 256 / H;
  constexpr int GROUP = C / 4;
  __shared__ __align__(16) float hs[4][8][256];
  __shared__ float attS[4][8][H], attD[4][8][H];
  const int wid = threadIdx.x >> 6, lane = threadIdx.x & 63;
  const int g = blockIdx.x * 4 + wid;
  const int base = g * 8;
  const int hd = lane / GROUP;
  float4 as4 = *reinterpret_cast<const float4*>(asv + lane * 4);
  float4 ad4 = *reinterpret_cast<const float4*>(adv + lane * 4);
#pragma unroll
  for (int i = 0; i < 8; ++i) {
    uint2 raw = *reinterpret_cast<const uint2*>(h + (size_t)(base + i) * 256 + lane * 4);
    float f0 = __uint_as_float(raw.x << 16);
    float f1 = __uint_as_float(raw.x & 0xFFFF0000u);
    float f2 = __uint_as_float(raw.y << 16);
    float f3 = __uint_as_float(raw.y & 0xFFFF0000u);
    *reinterpret_cast<float4*>(&hs[wid][i][lane * 4]) = make_float4(f0, f1, f2, f3);
    float ps = f0 * as4.x + f1 * as4.y + f2 * as4.z + f3 * as4.w;
    float pd = f0 * ad4.x + f1 * ad4.y + f2 * ad4.z + f3 * ad4.w;
#pragma unroll
    for (int o = GROUP / 2; o >= 1; o >>= 1) {
      ps += __shfl_xor(ps, o);
      pd += __shfl_xor(pd, o);
    }
    if ((lane & (GROUP - 1)) == 0) {
      attS[wid][i][hd] = ps;
      attD[wid][i][hd] = pd;
    }
  }
  __syncthreads();
  const float4 gv = *reinterpret_cast<const float4*>(lng + lane * 4);
  const float4 bv = *reinterpret_cast<const float4*>(lnb + lane * 4);
  const float4 biasv = *reinterpret_cast<const float4*>(bias + lane * 4);
  for (int i = 0; i < 8; ++i) {
    float ad = attD[wid][i][hd];
    float e[8];
    float mx = -1e30f;
#pragma unroll
    for (int j = 0; j < 8; ++j) {
      float v = attS[wid][j][hd] + ad;
      v = v > 0.f ? v : 0.2f * v;
      e[j] = v;
      mx = fmaxf(mx, v);
    }
    float sum = 0.f;
#pragma unroll
    for (int j = 0; j < 8; ++j) { e[j] = expf(e[j] - mx); sum += e[j]; }
    float inv = 1.f / (sum + 1e-16f);
    float a0 = 0, a1 = 0, a2 = 0, a3 = 0;
#pragma unroll
    for (int j = 0; j < 8; ++j) {
      float wj = e[j] * inv;
      float4 hv = *reinterpret_cast<const float4*>(&hs[wid][j][lane * 4]);
      a0 += wj * hv.x; a1 += wj * hv.y; a2 += wj * hv.z; a3 += wj * hv.w;
    }
    float4 xr = *reinterpret_cast<const float4*>(x + (size_t)(base + i) * 256 + lane * 4);
    float v0 = elu_f(a0 + biasv.x) + xr.x;
    float v1 = elu_f(a1 + biasv.y) + xr.y;
    float v2 = elu_f(a2 + biasv.z) + xr.z;
    float v3 = elu_f(a3 + biasv.w) + xr.w;
    float s = v0 + v1 + v2 + v3;
    float s2 = v0 * v0 + v1 * v1 + v2 * v2 + v3 * v3;
    s = warp_sum(s); s2 = warp_sum(s2);
    float mu = s * (1.f / 256.f);
    float var = s2 * (1.f / 256.f) - mu * mu;
    float rs = rsqrtf(var + 1e-5f);
    float4 o;
    o.x = (v0 - mu) * rs * gv.x + bv.x;
    o.y = (v1 - mu) * rs * gv.y + bv.y;
    o.z = (v2 - mu) * rs * gv.z + bv.z;
    o.w = (v3 - mu) * rs * gv.w + bv.w;
    *reinterpret_cast<float4*>(x + (size_t)(base + i) * 256 + lane * 4) = o;
    uint2 ob;
    ob.x = pkbf(o.x, o.y);
    ob.y = pkbf(o.z, o.w);
    *reinterpret_cast<uint2*>(xb16 + (size_t)(base + i) * 256 + lane * 4) = ob;
  }
}

__global__ __launch_bounds__(256) void pool_readout(const float* __restrict__ x,
    const float* __restrict__ rw, const float* __restrict__ rb,
    float* __restrict__ out) {
  int g = (blockIdx.x * blockDim.x + threadIdx.x) >> 6;
  int lane = threadIdx.x & 63;
  if (g >= NG) return;
  float a0 = 0, a1 = 0, a2 = 0, a3 = 0;
#pragma unroll
  for (int j = 0; j < 8; ++j) {
    float4 v = *reinterpret_cast<const float4*>(x + (size_t)(g * 8 + j) * 256 + lane * 4);
    a0 += v.x; a1 += v.y; a2 += v.z; a3 += v.w;
  }
  float4 w = *reinterpret_cast<const float4*>(rw + lane * 4);
  float p = (a0 * w.x + a1 * w.y + a2 * w.z + a3 * w.w) * 0.125f;
  p = warp_sum(p);
  if (lane == 0) out[g] = 1.f / (1.f + expf(-(p + rb[0])));
}

extern "C" void kernel_launch(void* const* d_in, const int* in_sizes, int n_in,
                              void* d_out, int out_size, void* d_ws, size_t ws_size,
                              hipStream_t stream) {
  const int* cat_ids = (const int*)d_in[0];
  const float* vf = (const float*)d_in[1];
  const float* cat_table = (const float*)d_in[4];
  const float* vp_w1 = (const float*)d_in[5];
  const float* vp_b1 = (const float*)d_in[6];
  const float* vp_w2 = (const float*)d_in[7];
  const float* vp_b2 = (const float*)d_in[8];
  const float* vp_lng = (const float*)d_in[9];
  const float* vp_lnb = (const float*)d_in[10];
  const float* c0_w = (const float*)d_in[11];
  const float* c0_as = (const float*)d_in[12];
  const float* c0_ad = (const float*)d_in[13];
  const float* c0_b = (const float*)d_in[14];
  const float* ln0_g = (const float*)d_in[15];
  const float* ln0_b = (const float*)d_in[16];
  const float* c1_w = (const float*)d_in[17];
  const float* c1_as = (const float*)d_in[18];
  const float* c1_ad = (const float*)d_in[19];
  const float* c1_b = (const float*)d_in[20];
  const float* ln1_g = (const float*)d_in[21];
  const float* ln1_b = (const float*)d_in[22];
  const float* ro_w = (const float*)d_in[23];
  const float* ro_b = (const float*)d_in[24];
  float* out = (float*)d_out;

  char* ws = (char*)d_ws;
  ushort* w1b = (ushort*)ws;   ws += (size_t)512 * 2048 * 2;
  ushort* w2b = (ushort*)ws;   ws += (size_t)128 * 512 * 2;
  ushort* c0wb = (ushort*)ws;  ws += (size_t)256 * 256 * 2;
  ushort* c1wb = (ushort*)ws;  ws += (size_t)256 * 256 * 2;
  ushort* v1b = (ushort*)ws;   ws += (size_t)NN * 512 * 2;
  ushort* v2b = (ushort*)ws;   ws += (size_t)NN * 128 * 2;
  float* xb = (float*)ws;      ws += (size_t)NN * 256 * 4;
  ushort* xbb = (ushort*)ws;   ws += (size_t)NN * 256 * 2;
  ushort* hbb = (ushort*)ws;

  dim3 b256(256), b512(512);
  const int RB = (NN + 127) / 128;        // 782
  const int RBpad = ((RB + 7) / 8) * 8;   // 784

  cvt_bf16<<<1024, b256, 0, stream>>>(vp_w1, w1b, 512 * 2048 / 4);
  cvt_bf16<<<64, b256, 0, stream>>>(vp_w2, w2b, 128 * 512 / 4);
  cvt_bf16<<<64, b256, 0, stream>>>(c0_w, c0wb, 256 * 256 / 4);
  cvt_bf16<<<64, b256, 0, stream>>>(c1_w, c1wb, 256 * 256 / 4);

  // v1 = relu(vf @ w1^T + b1): 128x512 blocks, A read once, B double-buffered
  gemm_f32p<true><<<RB, b512, 0, stream>>>(vf, w1b, vp_b1, v1b, NN, 2048);
  // v2 = v1 @ w2^T + b2
  gemm_glds<false, 1><<<RB, b256, 0, stream>>>(v1b, w2b, vp_b2, v2b,
                                               NN, 512, 128, RB);
  ln_concat<<<(NN * 64 + 255) / 256, b256, 0, stream>>>(v2b, vp_lng, vp_lnb,
                                                        cat_ids, cat_table, xb, xbb);

  gemm_glds<false, 2><<<RBpad * 2, b256, 0, stream>>>(xbb, c0wb, nullptr, hbb,
                                                      NN, 256, 256, RB);
  gat_fused<4><<<NG / 4, b256, 0, stream>>>(hbb, c0_as, c0_ad, c0_b, ln0_g, ln0_b, xb, xbb);

  gemm_glds<false, 2><<<RBpad * 2, b256, 0, stream>>>(xbb, c1wb, nullptr, hbb,
                                                      NN, 256, 256, RB);
  gat_fused<1><<<NG / 4, b256, 0, stream>>>(hbb, c1_as, c1_ad, c1_b, ln1_g, ln1_b, xb, xbb);

  pool_readout<<<NG / 4, b256, 0, stream>>>(xb, ro_w, ro_b, out);
}